// Round 3
// baseline (209.363 us; speedup 1.0000x reference)
//
#include <hip/hip_runtime.h>

typedef unsigned short u16;
typedef unsigned int u32;
typedef __attribute__((ext_vector_type(8))) short short8;   // 8 bf16 (MFMA A/B frag)
typedef __attribute__((ext_vector_type(4))) float f32x4;    // MFMA C/D frag
typedef __attribute__((ext_vector_type(4))) float fvec4;
typedef __attribute__((ext_vector_type(4))) u16 u16x4;

union S8U { u32 w[4]; short8 v; };

__device__ __forceinline__ u16 f2bf(float f) {
  u32 u = __float_as_uint(f);
  u += 0x7FFFu + ((u >> 16) & 1u);   // RTNE
  return (u16)(u >> 16);
}
__device__ __forceinline__ u32 cvtpk(float lo, float hi) {
  u32 r;
  asm("v_cvt_pk_bf16_f32 %0, %1, %2" : "=v"(r) : "v"(lo), "v"(hi));
  return r;
}
// wave-local LDS fence (buffers per-wave): drain this wave's ds ops, pin order.
__device__ __forceinline__ void wave_lds_fence() {
  asm volatile("s_waitcnt lgkmcnt(0)" ::: "memory");
  __builtin_amdgcn_sched_barrier(0);
}
// memory row index of token (Bg,h,w); rows of x are 256 elems.
__device__ __forceinline__ int m_of(int Bg, int h, int w) {
  return ((Bg >> 2) << 14) | ((h & 3) << 12) | ((((Bg & 3) << 1) | (h >> 5)) << 9) |
         (((h >> 2) & 7) << 6) | w;
}
__device__ __forceinline__ f32x4 mfma16(short8 a, short8 b, f32x4 c) {
  return __builtin_amdgcn_mfma_f32_16x16x32_bf16(a, b, c, 0, 0, 0);
}

// ---------------- prep: pack per-head weight slices (bf16) + transposed bias mats ----------
// wg layout (per group): [head g 0..3][sec s 0..2 (q,k,v)][c 0..31][kc 0..255]
__global__ void k_prep(const float* __restrict__ qkv_w, const float* __restrict__ t0,
                       const float* __restrict__ t1, u16* __restrict__ wg,
                       float* __restrict__ bias4T, float* __restrict__ bias8T) {
  int tid = blockIdx.x * 256 + threadIdx.x, stride = gridDim.x * 256;
  for (int i = tid; i < 196608; i += stride) {   // wg0 (grp0) then wg1 (grp1)
    int grp = i / 98304, rem = i - grp * 98304;
    int rowp = rem >> 8, kc = rem & 255;
    int g = rowp / 96, sub = rowp - g * 96, s = sub >> 5, c = sub & 31;
    int srow = s * 256 + grp * 128 + g * 32 + c;
    wg[i] = f2bf(qkv_w[srow * 256 + kc]);
  }
  for (int i = tid; i < 16384; i += stride) {    // bias8T[g][m][n]
    int g = i >> 12, m = (i >> 6) & 63, n = i & 63;
    int di = (n >> 3) - (m >> 3) + 7, dj = (n & 7) - (m & 7) + 7;
    bias8T[i] = t1[(di * 15 + dj) * 4 + g];
  }
  for (int i = tid; i < 1024; i += stride) {     // bias4T[g][m][n]
    int g = i >> 8, m = (i >> 4) & 15, n = i & 15;
    int di = (n >> 2) - (m >> 2) + 3, dj = (n & 3) - (m & 3) + 3;
    bias4T[i] = t0[(di * 7 + dj) * 4 + g];
  }
}

// ---------------- fused qkv-GEMM + attention, ws=8 (group 1, channels 128..255) -----------
// block = 1 window (1024 blocks), 512 thr = 8 waves; wave = (head g, token-half mh)
__global__ __launch_bounds__(512, 4) void k_fa8(const float* __restrict__ x,
                                                const u16* __restrict__ wg1,
                                                const float* __restrict__ qkv_b,
                                                const float* __restrict__ bias8T,
                                                float* __restrict__ out) {
  __shared__ __align__(16) u16 regB[4][64 * 72];  // per-head: q|k [64][72] -> P [64][72] -> O f32 (per-half)
  __shared__ __align__(16) u16 vt[4][32 * 72];    // per-head V^T [e][tok]
  const int bid = blockIdx.x;
  const int Bg = bid >> 6, wi = (bid >> 3) & 7, wj = bid & 7;
  const int h0 = wi * 8, w0 = wj * 8;
  const int wv = threadIdx.x >> 6, l = threadIdx.x & 63;
  const int g = wv >> 1, mh = wv & 1;
  const int lr = l & 15, lk4 = l >> 4;
  u16* qkh = regB[g];
  u16* vtg = vt[g];
  const f32x4 z = {0.f, 0.f, 0.f, 0.f};

  // ---- GEMM: 32 tokens (this half) x 96 cols (this head's q,k,v) x K=256 ----
  const float* xr0;
  const float* xr1;
  {
    int t0_ = mh * 32 + lr, t1_ = mh * 32 + 16 + lr;
    xr0 = x + (size_t)m_of(Bg, h0 + (t0_ >> 3), w0 + (t0_ & 7)) * 256 + lk4 * 8;
    xr1 = x + (size_t)m_of(Bg, h0 + (t1_ >> 3), w0 + (t1_ & 7)) * 256 + lk4 * 8;
  }
  const u16* bp = wg1 + (size_t)(g * 96 + lr) * 256 + lk4 * 8;
  float bias_b[6];
#pragma unroll
  for (int j = 0; j < 6; ++j)
    bias_b[j] = qkv_b[(j >> 1) * 256 + 128 + g * 32 + (j & 1) * 16 + lr];

  f32x4 acc[6][2];
#pragma unroll
  for (int j = 0; j < 6; ++j) { acc[j][0] = z; acc[j][1] = z; }
#pragma unroll
  for (int kk = 0; kk < 256; kk += 32) {
    short8 a0, a1;
    {
      fvec4 v0 = *(const fvec4*)(xr0 + kk);
      fvec4 v1 = *(const fvec4*)(xr0 + kk + 4);
      S8U u; u.w[0] = cvtpk(v0[0], v0[1]); u.w[1] = cvtpk(v0[2], v0[3]);
      u.w[2] = cvtpk(v1[0], v1[1]); u.w[3] = cvtpk(v1[2], v1[3]);
      a0 = u.v;
    }
    {
      fvec4 v0 = *(const fvec4*)(xr1 + kk);
      fvec4 v1 = *(const fvec4*)(xr1 + kk + 4);
      S8U u; u.w[0] = cvtpk(v0[0], v0[1]); u.w[1] = cvtpk(v0[2], v0[3]);
      u.w[2] = cvtpk(v1[0], v1[1]); u.w[3] = cvtpk(v1[2], v1[3]);
      a1 = u.v;
    }
#pragma unroll
    for (int j = 0; j < 6; ++j) {
      short8 b = *(const short8*)(bp + (j >> 1) * 8192 + (j & 1) * 4096 + kk);
      acc[j][0] = mfma16(a0, b, acc[j][0]);
      acc[j][1] = mfma16(a1, b, acc[j][1]);
    }
  }
  // ---- stage q,k -> qkh [tok][q0..31|k32..63]; v -> vt [e][tok] ----
#pragma unroll
  for (int j = 0; j < 4; ++j) {
    int colbase = (j < 2) ? (j * 16 + lr) : (32 + (j - 2) * 16 + lr);
#pragma unroll
    for (int il = 0; il < 2; ++il) {
      int tok = mh * 32 + il * 16 + lk4 * 4;
#pragma unroll
      for (int r = 0; r < 4; ++r)
        qkh[(tok + r) * 72 + colbase] = f2bf(acc[j][il][r] + bias_b[j]);
    }
  }
#pragma unroll
  for (int j2 = 0; j2 < 2; ++j2)
#pragma unroll
    for (int il = 0; il < 2; ++il) {
      u16x4 pv;
#pragma unroll
      for (int r = 0; r < 4; ++r) pv[r] = f2bf(acc[4 + j2][il][r] + bias_b[4 + j2]);
      *(u16x4*)&vtg[(j2 * 16 + lr) * 72 + mh * 32 + il * 16 + lk4 * 4] = pv;
    }
  __syncthreads();  // B1: qkh/vt staged by both waves of the pair

  // ---- S^T = K·Q^T (8 MFMAs): value (m = tm*16+lk4*4+r, n = mh*32+tn*16+lr) ----
  short8 kf[4], qf[2];
#pragma unroll
  for (int tm = 0; tm < 4; ++tm)
    kf[tm] = *(const short8*)&qkh[(tm * 16 + lr) * 72 + 32 + lk4 * 8];
#pragma unroll
  for (int tn = 0; tn < 2; ++tn)
    qf[tn] = *(const short8*)&qkh[(mh * 32 + tn * 16 + lr) * 72 + lk4 * 8];
  f32x4 s[4][2];
#pragma unroll
  for (int tm = 0; tm < 4; ++tm)
#pragma unroll
    for (int tn = 0; tn < 2; ++tn) s[tm][tn] = mfma16(kf[tm], qf[tn], z);

  const float scale = 0.17677669529663687f;  // 1/sqrt(32)
#pragma unroll
  for (int tm = 0; tm < 4; ++tm)
#pragma unroll
    for (int tn = 0; tn < 2; ++tn)
#pragma unroll
      for (int r = 0; r < 4; ++r) {
        int m = tm * 16 + lk4 * 4 + r, n = mh * 32 + tn * 16 + lr;
        s[tm][tn][r] = s[tm][tn][r] * scale + bias8T[(g * 64 + m) * 64 + n];
      }
  // softmax over m: in-lane 16 + xor16 + xor32; fold 1/den into P
  float inv[2];
#pragma unroll
  for (int tn = 0; tn < 2; ++tn) {
    float mx = -1e30f;
#pragma unroll
    for (int tm = 0; tm < 4; ++tm)
#pragma unroll
      for (int r = 0; r < 4; ++r) mx = fmaxf(mx, s[tm][tn][r]);
    mx = fmaxf(mx, __shfl_xor(mx, 16));
    mx = fmaxf(mx, __shfl_xor(mx, 32));
    float sm = 0.f;
#pragma unroll
    for (int tm = 0; tm < 4; ++tm)
#pragma unroll
      for (int r = 0; r < 4; ++r) {
        float p = __expf(s[tm][tn][r] - mx);
        s[tm][tn][r] = p;
        sm += p;
      }
    sm += __shfl_xor(sm, 16);
    sm += __shfl_xor(sm, 32);
    inv[tn] = 1.f / sm;
  }
  __syncthreads();  // B2: both waves done reading q/k before P overlays the region

  // ---- P (own n-rows, all m) -> overlay on qkh ----
#pragma unroll
  for (int tn = 0; tn < 2; ++tn)
#pragma unroll
    for (int tm = 0; tm < 4; ++tm) {
      u16x4 pk;
#pragma unroll
      for (int r = 0; r < 4; ++r) pk[r] = f2bf(s[tm][tn][r] * inv[tn]);
      *(u16x4*)&qkh[(mh * 32 + tn * 16 + lr) * 72 + tm * 16 + lk4 * 4] = pk;
    }
  wave_lds_fence();

  // ---- O = P·V (8 MFMAs): value (n = mh*32+tn*16+lk4*4+r, e = te*16+lr) ----
  f32x4 o[2][2];
#pragma unroll
  for (int tn = 0; tn < 2; ++tn) { o[tn][0] = z; o[tn][1] = z; }
#pragma unroll
  for (int ks = 0; ks < 2; ++ks) {
    short8 pa[2], vb[2];
#pragma unroll
    for (int tn = 0; tn < 2; ++tn)
      pa[tn] = *(const short8*)&qkh[(mh * 32 + tn * 16 + lr) * 72 + ks * 32 + lk4 * 8];
#pragma unroll
    for (int te = 0; te < 2; ++te)
      vb[te] = *(const short8*)&vtg[(te * 16 + lr) * 72 + ks * 32 + lk4 * 8];
#pragma unroll
    for (int tn = 0; tn < 2; ++tn)
#pragma unroll
      for (int te = 0; te < 2; ++te) o[tn][te] = mfma16(pa[tn], vb[te], o[tn][te]);
  }
  // ---- O transpose via own-half overlay (f32 [32][33]) ----
  float* olh = (float*)qkh + mh * 1152;
#pragma unroll
  for (int tn = 0; tn < 2; ++tn)
#pragma unroll
    for (int te = 0; te < 2; ++te)
#pragma unroll
      for (int r = 0; r < 4; ++r)
        olh[(tn * 16 + lk4 * 4 + r) * 33 + te * 16 + lr] = o[tn][te][r];
  wave_lds_fence();
  // ---- store: lane = token (own half), 16 e's each; 32B runs along w ----
  {
    int t = mh * 32 + (l & 31);
    int h = h0 + (t >> 3), w = w0 + (t & 7);
    size_t base = ((size_t)(Bg >> 2)) * 4194304 + (size_t)((Bg & 3) * 2 + (h >> 5)) * 131072 +
                  (size_t)((h >> 2) & 7) * 16384 + (size_t)((h & 3) * 64 + w);
    int e0 = (l >> 5) * 16;
    const float* orow = (const float*)qkh + mh * 1152 + (t & 31) * 33;
#pragma unroll
    for (int ee = 0; ee < 16; ++ee) {
      int c = 128 + g * 32 + e0 + ee;
      size_t idx = base + (size_t)(c >> 6) * 1048576 + (size_t)((c >> 3) & 7) * 2048 +
                   (size_t)(c & 7) * 256;
      out[idx] = orow[e0 + ee];
    }
  }
}

// ---------------- fused qkv-GEMM + attention, ws=4 (group 0, channels 0..127) -------------
// 512 blocks x 512 thr = 8 waves; wave = 1 window (16 tokens), heads looped; all per-wave
__global__ __launch_bounds__(512, 4) void k_fa4(const float* __restrict__ x,
                                                const u16* __restrict__ wg0,
                                                const float* __restrict__ qkv_b,
                                                const float* __restrict__ bias4T,
                                                float* __restrict__ out) {
  __shared__ __align__(16) u16 qk[8][16 * 72];   // per-wave q|k; later O f32 [16][33]
  __shared__ __align__(16) u16 pl[8][16 * 40];   // per-wave P [n][m(32, hi 16 zero)]
  __shared__ __align__(16) u16 vt[8][32 * 40];   // per-wave V^T [e][m(32, hi 16 zero)]
  const int wv = threadIdx.x >> 6, l = threadIdx.x & 63;
  const int wid = blockIdx.x * 8 + wv;
  const int Bg = wid >> 8, wi = (wid >> 4) & 15, wj = wid & 15;
  const int h0 = wi * 4, w0 = wj * 4;
  const int lr = l & 15, lk4 = l >> 4;
  u16* qkw = qk[wv];
  u16* plw = pl[wv];
  u16* vtw = vt[wv];
  const f32x4 z = {0.f, 0.f, 0.f, 0.f};
  const float scale = 0.17677669529663687f;

  // zero the K-padding (cols 16..31) of P and V^T once; later writes never touch it
  {
    u16x4 z4 = {0, 0, 0, 0};
    *(u16x4*)&plw[(l & 15) * 40 + 16 + (l >> 4) * 4] = z4;
    *(u16x4*)&vtw[(l & 31) * 40 + 16 + (l >> 5) * 8] = z4;
    *(u16x4*)&vtw[(l & 31) * 40 + 20 + (l >> 5) * 8] = z4;
  }
  const float* xr = x + (size_t)m_of(Bg, h0 + (lr >> 2), w0 + (lr & 3)) * 256 + lk4 * 8;

  for (int g = 0; g < 4; ++g) {
    const u16* bp = wg0 + (size_t)(g * 96 + lr) * 256 + lk4 * 8;
    float bias_b[6];
#pragma unroll
    for (int j = 0; j < 6; ++j)
      bias_b[j] = qkv_b[(j >> 1) * 256 + g * 32 + (j & 1) * 16 + lr];
    f32x4 acc[6];
#pragma unroll
    for (int j = 0; j < 6; ++j) acc[j] = z;
#pragma unroll
    for (int kk = 0; kk < 256; kk += 32) {
      fvec4 v0 = *(const fvec4*)(xr + kk);
      fvec4 v1 = *(const fvec4*)(xr + kk + 4);
      S8U u; u.w[0] = cvtpk(v0[0], v0[1]); u.w[1] = cvtpk(v0[2], v0[3]);
      u.w[2] = cvtpk(v1[0], v1[1]); u.w[3] = cvtpk(v1[2], v1[3]);
      short8 a = u.v;
#pragma unroll
      for (int j = 0; j < 6; ++j) {
        short8 b = *(const short8*)(bp + (j >> 1) * 8192 + (j & 1) * 4096 + kk);
        acc[j] = mfma16(a, b, acc[j]);
      }
    }
    // stage q,k -> qkw; v -> vtw
#pragma unroll
    for (int j = 0; j < 4; ++j) {
      int colbase = (j < 2) ? (j * 16 + lr) : (32 + (j - 2) * 16 + lr);
#pragma unroll
      for (int r = 0; r < 4; ++r)
        qkw[(lk4 * 4 + r) * 72 + colbase] = f2bf(acc[j][r] + bias_b[j]);
    }
#pragma unroll
    for (int j2 = 0; j2 < 2; ++j2) {
      u16x4 pv;
#pragma unroll
      for (int r = 0; r < 4; ++r) pv[r] = f2bf(acc[4 + j2][r] + bias_b[4 + j2]);
      *(u16x4*)&vtw[(j2 * 16 + lr) * 40 + lk4 * 4] = pv;
    }
    wave_lds_fence();
    // S^T = K·Q^T (1 MFMA): (m = lk4*4+r, n = lr)
    short8 kf = *(const short8*)&qkw[lr * 72 + 32 + lk4 * 8];
    short8 qf = *(const short8*)&qkw[lr * 72 + lk4 * 8];
    f32x4 s = mfma16(kf, qf, z);
#pragma unroll
    for (int r = 0; r < 4; ++r) {
      int m = lk4 * 4 + r;
      s[r] = s[r] * scale + bias4T[(g * 16 + m) * 16 + lr];
    }
    float mx = fmaxf(fmaxf(s[0], s[1]), fmaxf(s[2], s[3]));
    mx = fmaxf(mx, __shfl_xor(mx, 16));
    mx = fmaxf(mx, __shfl_xor(mx, 32));
    float sm = 0.f;
#pragma unroll
    for (int r = 0; r < 4; ++r) { s[r] = __expf(s[r] - mx); sm += s[r]; }
    sm += __shfl_xor(sm, 16);
    sm += __shfl_xor(sm, 32);
    float inv = 1.f / sm;
    u16x4 pk4;
#pragma unroll
    for (int r = 0; r < 4; ++r) pk4[r] = f2bf(s[r] * inv);
    *(u16x4*)&plw[lr * 40 + lk4 * 4] = pk4;
    wave_lds_fence();
    // O = P·V (2 MFMAs, K zero-padded to 32): (n = lk4*4+r, e = te*16+lr)
    short8 pa = *(const short8*)&plw[lr * 40 + lk4 * 8];
    f32x4 o[2];
#pragma unroll
    for (int te = 0; te < 2; ++te) {
      short8 vb = *(const short8*)&vtw[(te * 16 + lr) * 40 + lk4 * 8];
      o[te] = mfma16(pa, vb, z);
    }
    float* olw = (float*)qkw;  // overlay (q,k dead)
#pragma unroll
    for (int te = 0; te < 2; ++te)
#pragma unroll
      for (int r = 0; r < 4; ++r)
        olw[(lk4 * 4 + r) * 33 + te * 16 + lr] = o[te][r];
    wave_lds_fence();
    // store: lane = (token lr) x (e-chunk lk4)
    {
      int h = h0 + (lr >> 2), w = w0 + (lr & 3);
      size_t base = ((size_t)(Bg >> 2)) * 4194304 + (size_t)((Bg & 3) * 2 + (h >> 5)) * 131072 +
                    (size_t)((h >> 2) & 7) * 16384 + (size_t)((h & 3) * 64 + w);
#pragma unroll
      for (int ee = 0; ee < 8; ++ee) {
        int c = g * 32 + lk4 * 8 + ee;
        size_t idx = base + (size_t)(c >> 6) * 1048576 + (size_t)((c >> 3) & 7) * 2048 +
                     (size_t)(c & 7) * 256;
        out[idx] = olw[lr * 33 + lk4 * 8 + ee];
      }
    }
    wave_lds_fence();  // protect per-wave buffer reuse across g iterations
  }
}

extern "C" void kernel_launch(void* const* d_in, const int* in_sizes, int n_in,
                              void* d_out, int out_size, void* d_ws, size_t ws_size,
                              hipStream_t stream) {
  const float* x = (const float*)d_in[0];
  const float* qkv_w = (const float*)d_in[1];
  const float* qkv_b = (const float*)d_in[2];
  const float* t0 = (const float*)d_in[3];
  const float* t1 = (const float*)d_in[4];
  float* out = (float*)d_out;
  char* ws = (char*)d_ws;

  u16* wg = (u16*)ws;                        // wg0: 98304 elems, wg1: next 98304 (393216 B)
  u16* wg0 = wg;
  u16* wg1 = wg + 98304;
  float* bias8T = (float*)(ws + 393216);     // 4*64*64*4 = 65536 B
  float* bias4T = (float*)(ws + 458752);     // 4*16*16*4 = 4096 B

  k_prep<<<256, 256, 0, stream>>>(qkv_w, t0, t1, wg, bias4T, bias8T);
  k_fa8<<<1024, 512, 0, stream>>>(x, wg1, qkv_b, bias8T, out);
  k_fa4<<<512, 512, 0, stream>>>(x, wg0, qkv_b, bias4T, out);
}

// Round 4
// 173.838 us; speedup vs baseline: 1.2044x; 1.2044x over previous
//
#include <hip/hip_runtime.h>

typedef unsigned short u16;
typedef unsigned int u32;
typedef __attribute__((ext_vector_type(8))) short short8;   // 8 bf16 (MFMA A/B frag)
typedef __attribute__((ext_vector_type(4))) float f32x4;    // MFMA C/D frag
typedef __attribute__((ext_vector_type(4))) float fvec4;
typedef __attribute__((ext_vector_type(4))) u16 u16x4;

__device__ __forceinline__ u16 f2bf(float f) {
  u32 u = __float_as_uint(f);
  u += 0x7FFFu + ((u >> 16) & 1u);   // RTNE
  return (u16)(u >> 16);
}

// wave-local LDS fence: buffers are per-wave, so a full barrier is overkill.
__device__ __forceinline__ void wave_lds_fence() {
  asm volatile("s_waitcnt lgkmcnt(0)" ::: "memory");
  __builtin_amdgcn_sched_barrier(0);
}

// memory row index of token (Bg,h,w); rows of x / qkv are 256 / 768 elems.
__device__ __forceinline__ int m_of(int Bg, int h, int w) {
  return ((Bg >> 2) << 14) | ((h & 3) << 12) | ((((Bg & 3) << 1) | (h >> 5)) << 9) |
         (((h >> 2) & 7) << 6) | w;
}

__device__ __forceinline__ f32x4 mfma16(short8 a, short8 b, f32x4 c) {
  return __builtin_amdgcn_mfma_f32_16x16x32_bf16(a, b, c, 0, 0, 0);
}

// ---------------- prep: convert W to bf16, materialize bias matrices ----------------
__global__ void k_prep(const float* __restrict__ qkv_w, const float* __restrict__ t0,
                       const float* __restrict__ t1, u16* __restrict__ wb,
                       float* __restrict__ bias4, float* __restrict__ bias8) {
  int tid = blockIdx.x * 256 + threadIdx.x;
  int stride = gridDim.x * 256;
  for (int i = tid; i < 768 * 256; i += stride) wb[i] = f2bf(qkv_w[i]);
  for (int i = tid; i < 4 * 64 * 64; i += stride) {
    int g = i >> 12, n = (i >> 6) & 63, m = i & 63;
    int di = (n >> 3) - (m >> 3) + 7, dj = (n & 7) - (m & 7) + 7;
    bias8[i] = t1[(di * 15 + dj) * 4 + g];
  }
  for (int i = tid; i < 4 * 16 * 16; i += stride) {
    int g = i >> 8, n = (i >> 4) & 15, m = i & 15;
    int di = (n >> 2) - (m >> 2) + 3, dj = (n & 3) - (m & 3) + 3;
    bias4[i] = t0[(di * 7 + dj) * 4 + g];
  }
}

// ---------------- QKV GEMM: [65536 x 256] x [256 x 768] -> bf16 qkv[m][768] ----------------
// Block = 64 rows x full 768 cols. x staged to LDS once (1 barrier). B streamed from
// L2-resident wb with a register double-buffer. Swapped mfma(b,a) so the accumulator's
// reg-dim is the output COLUMN -> 8B packed stores, no transpose needed.
__global__ __launch_bounds__(256) void k_gemm(const float* __restrict__ x,
                                              const u16* __restrict__ wb,
                                              const float* __restrict__ qkv_b,
                                              u16* __restrict__ qkv) {
  __shared__ __align__(16) u16 As[64 * 264];  // stride 264: 16B-aligned rows
  const int t = threadIdx.x;
  const int wid = t >> 6, l = t & 63;
  const int lr = l & 15, lk4 = l >> 4;
  const size_t xbase = (size_t)blockIdx.x * 64 * 256;

  // stage A: fully-coalesced f32 reads (1KB/instr), bf16 LDS writes
  {
    const float* xp = x + xbase + t * 4;
    const int c = (t & 63) * 4;
#pragma unroll
    for (int it = 0; it < 16; ++it) {
      fvec4 v = *(const fvec4*)(xp + it * 1024);
      int r = wid + it * 4;
      u16x4 u;
      u[0] = f2bf(v[0]); u[1] = f2bf(v[1]); u[2] = f2bf(v[2]); u[3] = f2bf(v[3]);
      *(u16x4*)&As[r * 264 + c] = u;
    }
  }
  __syncthreads();  // the only barrier in this kernel

  const int wm = (wid & 1) * 32;          // wave covers rows wm..wm+31
  const int wcol = (wid >> 1) * 64;       // and 64 of the 128 cols of each nt chunk
  const int growbase = blockIdx.x * 64 + wm;
  const f32x4 z = {0.f, 0.f, 0.f, 0.f};

  for (int nt = 0; nt < 6; ++nt) {
    const int c0 = nt * 128 + wcol;
    const u16* bbase = wb + (size_t)(c0 + lr) * 256 + lk4 * 8;
    f32x4 acc[4][2];
#pragma unroll
    for (int jt = 0; jt < 4; ++jt) { acc[jt][0] = z; acc[jt][1] = z; }

    short8 bcur[4];
#pragma unroll
    for (int jt = 0; jt < 4; ++jt) bcur[jt] = *(const short8*)(bbase + jt * 4096);

#pragma unroll
    for (int kk = 0; kk < 256; kk += 32) {
      short8 bnxt[4];
      if (kk < 224) {
#pragma unroll
        for (int jt = 0; jt < 4; ++jt)
          bnxt[jt] = *(const short8*)(bbase + jt * 4096 + kk + 32);
      }
      short8 a0 = *(const short8*)&As[(wm + lr) * 264 + kk + lk4 * 8];
      short8 a1 = *(const short8*)&As[(wm + 16 + lr) * 264 + kk + lk4 * 8];
#pragma unroll
      for (int jt = 0; jt < 4; ++jt) {
        acc[jt][0] = mfma16(bcur[jt], a0, acc[jt][0]);  // reg-dim = col, lane-dim = row
        acc[jt][1] = mfma16(bcur[jt], a1, acc[jt][1]);
      }
      if (kk < 224) {
#pragma unroll
        for (int jt = 0; jt < 4; ++jt) bcur[jt] = bnxt[jt];
      }
    }
    // epilogue: + bias, pack 4 consecutive cols -> one 8B store per (jt,it)
#pragma unroll
    for (int jt = 0; jt < 4; ++jt) {
      int col0 = c0 + jt * 16 + lk4 * 4;
      fvec4 bb = *(const fvec4*)(qkv_b + col0);
#pragma unroll
      for (int it = 0; it < 2; ++it) {
        int row = growbase + it * 16 + lr;
        u16x4 u;
#pragma unroll
        for (int r = 0; r < 4; ++r) u[r] = f2bf(acc[jt][it][r] + bb[r]);
        *(u16x4*)&qkv[(size_t)row * 768 + col0] = u;
      }
    }
  }
}

// ---------------- attention ws=8 (group 1, channels 128..255) ----------------
// block = 1 window (1024 blocks), wave = head; all LDS buffers per-wave -> no barriers
__global__ __launch_bounds__(256) void k_attn8(const u16* __restrict__ qkv,
                                               const float* __restrict__ bias8,
                                               float* __restrict__ out) {
  __shared__ __align__(16) u16 vt[4 * 32 * 72];  // per-wave V^T [e][m] (pad 8)
  __shared__ __align__(16) u16 pl[4 * 64 * 72];  // per-wave P [n][m]; reused as O f32 [64][33]
  int bid = blockIdx.x;
  int Bg = bid >> 6, wi = (bid >> 3) & 7, wj = bid & 7;
  int h0 = wi * 8, w0 = wj * 8;
  int g = threadIdx.x >> 6, l = threadIdx.x & 63;
  int lr = l & 15, lk4 = l >> 4;
  u16* vtg = vt + g * (32 * 72);
  u16* plg = pl + g * (64 * 72);

  // load Q,K fragments straight from global (A-layout: row=l&15, k-chunk=(l>>4)*8)
  short8 aq[4], bk[4];
#pragma unroll
  for (int tn = 0; tn < 4; ++tn) {
    int n = tn * 16 + lr;
    int h = h0 + (n >> 3), w = w0 + (n & 7);
    const u16* row = qkv + (size_t)m_of(Bg, h, w) * 768;
    aq[tn] = *(const short8*)(row + 128 + g * 32 + lk4 * 8);
    bk[tn] = *(const short8*)(row + 384 + g * 32 + lk4 * 8);
  }
  // stage V^T: lane l owns token m=l
  {
    int h = h0 + (l >> 3), w = w0 + (l & 7);
    const u16* vrow = qkv + (size_t)m_of(Bg, h, w) * 768 + 640 + g * 32;
    short8 v0 = *(const short8*)(vrow);
    short8 v1 = *(const short8*)(vrow + 8);
    short8 v2 = *(const short8*)(vrow + 16);
    short8 v3 = *(const short8*)(vrow + 24);
#pragma unroll
    for (int j = 0; j < 8; ++j) {
      vtg[(0 + j) * 72 + l] = (u16)v0[j];
      vtg[(8 + j) * 72 + l] = (u16)v1[j];
      vtg[(16 + j) * 72 + l] = (u16)v2[j];
      vtg[(24 + j) * 72 + l] = (u16)v3[j];
    }
  }
  // S = q k^T  (16 MFMAs)
  f32x4 z = {0.f, 0.f, 0.f, 0.f};
  f32x4 s[4][4];
#pragma unroll
  for (int tn = 0; tn < 4; ++tn)
#pragma unroll
    for (int tm = 0; tm < 4; ++tm) s[tn][tm] = mfma16(aq[tn], bk[tm], z);

  const float scale = 0.17677669529663687f;  // 1/sqrt(32)
#pragma unroll
  for (int tn = 0; tn < 4; ++tn)
#pragma unroll
    for (int tm = 0; tm < 4; ++tm)
#pragma unroll
      for (int r = 0; r < 4; ++r) {
        int n = tn * 16 + lk4 * 4 + r, m = tm * 16 + lr;
        s[tn][tm][r] = s[tn][tm][r] * scale + bias8[(g * 64 + n) * 64 + m];
      }
  // softmax over m (row n lives in 16 lanes sharing l>>4)
  float invden[4][4];
#pragma unroll
  for (int tn = 0; tn < 4; ++tn)
#pragma unroll
    for (int r = 0; r < 4; ++r) {
      float mx = fmaxf(fmaxf(s[tn][0][r], s[tn][1][r]), fmaxf(s[tn][2][r], s[tn][3][r]));
#pragma unroll
      for (int d = 1; d < 16; d <<= 1) mx = fmaxf(mx, __shfl_xor(mx, d));
      float sum = 0.f;
#pragma unroll
      for (int tm = 0; tm < 4; ++tm) {
        float p = __expf(s[tn][tm][r] - mx);
        s[tn][tm][r] = p;
        sum += p;
      }
#pragma unroll
      for (int d = 1; d < 16; d <<= 1) sum += __shfl_xor(sum, d);
      invden[tn][r] = 1.f / sum;
    }
  // P -> LDS (bf16)
#pragma unroll
  for (int tn = 0; tn < 4; ++tn)
#pragma unroll
    for (int tm = 0; tm < 4; ++tm)
#pragma unroll
      for (int r = 0; r < 4; ++r)
        plg[(tn * 16 + lk4 * 4 + r) * 72 + tm * 16 + lr] = f2bf(s[tn][tm][r]);
  wave_lds_fence();
  // O = P V  (16 MFMAs)
  f32x4 o[4][2];
#pragma unroll
  for (int tn = 0; tn < 4; ++tn) { o[tn][0] = z; o[tn][1] = z; }
#pragma unroll
  for (int kc = 0; kc < 2; ++kc) {
    short8 pa[4], vb[2];
#pragma unroll
    for (int tn = 0; tn < 4; ++tn)
      pa[tn] = *(const short8*)&plg[(tn * 16 + lr) * 72 + kc * 32 + lk4 * 8];
#pragma unroll
    for (int te = 0; te < 2; ++te)
      vb[te] = *(const short8*)&vtg[(te * 16 + lr) * 72 + kc * 32 + lk4 * 8];
#pragma unroll
    for (int tn = 0; tn < 4; ++tn)
#pragma unroll
      for (int te = 0; te < 2; ++te) o[tn][te] = mfma16(pa[tn], vb[te], o[tn][te]);
  }
  wave_lds_fence();
  // scale by 1/denom, transpose O through LDS (overlay on plg)
  float* ol = (float*)plg;  // [64][33]
#pragma unroll
  for (int tn = 0; tn < 4; ++tn)
#pragma unroll
    for (int te = 0; te < 2; ++te)
#pragma unroll
      for (int r = 0; r < 4; ++r) {
        int n = tn * 16 + lk4 * 4 + r;
        ol[n * 33 + te * 16 + lr] = o[tn][te][r] * invden[tn][r];
      }
  wave_lds_fence();
  // store: lane = token, loop e -> 32B-chunk coalesced runs along w
  {
    int h = h0 + (l >> 3), w = w0 + (l & 7);
    size_t base = ((size_t)(Bg >> 2)) * 4194304 + (size_t)(((Bg & 3) * 2 + (h >> 5))) * 131072 +
                  (size_t)(((h >> 2) & 7)) * 16384 + (size_t)((h & 3) * 64 + w);
#pragma unroll
    for (int e = 0; e < 32; ++e) {
      int c = 128 + g * 32 + e;
      size_t idx = base + (size_t)(c >> 6) * 1048576 + (size_t)((c >> 3) & 7) * 2048 +
                   (size_t)(c & 7) * 256;
      out[idx] = ol[l * 33 + e];
    }
  }
}

// ---------------- attention ws=4 (group 0, channels 0..127) ----------------
// block = 4 windows (1024 blocks), wave = window, heads looped; per-wave buffers -> no barriers
__global__ __launch_bounds__(256) void k_attn4(const u16* __restrict__ qkv,
                                               const float* __restrict__ bias4,
                                               float* __restrict__ out) {
  __shared__ __align__(16) u16 vt[4 * 32 * 40];   // per-wave V^T [e][m0..32] (m 16..31 zero)
  __shared__ __align__(16) u16 pl[4 * 16 * 40];   // per-wave P [n][m0..32] (m 16..31 zero)
  __shared__ __align__(16) float ol[4 * 16 * 33]; // per-wave O
  int wv = threadIdx.x >> 6, l = threadIdx.x & 63;
  int wid = blockIdx.x * 4 + wv;
  int Bg = wid >> 8, wi = (wid >> 4) & 15, wj = wid & 15;
  int h0 = wi * 4, w0 = wj * 4;
  int lr = l & 15, lk4 = l >> 4;
  u16* vtw = vt + wv * (32 * 40);
  u16* plw = pl + wv * (16 * 40);
  float* olw = ol + wv * (16 * 33);
  f32x4 z = {0.f, 0.f, 0.f, 0.f};
  short8 z8 = {0, 0, 0, 0, 0, 0, 0, 0};
  const float scale = 0.17677669529663687f;

  // per-lane token addresses
  int hq = h0 + (lr >> 2), wq = w0 + (lr & 3);
  const u16* rowq = qkv + (size_t)m_of(Bg, hq, wq) * 768;

  for (int g = 0; g < 4; ++g) {
    short8 aq = *(const short8*)(rowq + g * 32 + lk4 * 8);
    short8 bk = *(const short8*)(rowq + 256 + g * 32 + lk4 * 8);
    // stage V^T: lane = (token lr) x (e-chunk lk4)
    {
      short8 v = *(const short8*)(rowq + 512 + g * 32 + lk4 * 8);
#pragma unroll
      for (int j = 0; j < 8; ++j) vtw[(lk4 * 8 + j) * 40 + lr] = (u16)v[j];
      // zero pad m in [16,32)
      *(short8*)&vtw[(l >> 1) * 40 + 16 + (l & 1) * 8] = z8;
    }
    // S (1 MFMA), C rows n = lk4*4+r, cols m = lr
    f32x4 s = mfma16(aq, bk, z);
#pragma unroll
    for (int r = 0; r < 4; ++r) {
      int n = lk4 * 4 + r;
      s[r] = s[r] * scale + bias4[(g * 16 + n) * 16 + lr];
    }
    float invden[4];
#pragma unroll
    for (int r = 0; r < 4; ++r) {
      float mx = s[r];
#pragma unroll
      for (int d = 1; d < 16; d <<= 1) mx = fmaxf(mx, __shfl_xor(mx, d));
      float p = __expf(s[r] - mx);
      s[r] = p;
      float sum = p;
#pragma unroll
      for (int d = 1; d < 16; d <<= 1) sum += __shfl_xor(sum, d);
      invden[r] = 1.f / sum;
    }
    // P -> LDS + zero pad
#pragma unroll
    for (int r = 0; r < 4; ++r) plw[(lk4 * 4 + r) * 40 + lr] = f2bf(s[r]);
    *(u16x4*)&plw[lr * 40 + 16 + lk4 * 4] = (u16x4){0, 0, 0, 0};
    wave_lds_fence();
    // O = P V : 2 MFMAs (te halves), K zero-padded to 32
    f32x4 o[2];
#pragma unroll
    for (int te = 0; te < 2; ++te) {
      short8 pa = *(const short8*)&plw[lr * 40 + lk4 * 8];
      short8 vb = *(const short8*)&vtw[(te * 16 + lr) * 40 + lk4 * 8];
      o[te] = mfma16(pa, vb, z);
    }
#pragma unroll
    for (int te = 0; te < 2; ++te)
#pragma unroll
      for (int r = 0; r < 4; ++r) {
        int n = lk4 * 4 + r;
        olw[n * 33 + te * 16 + lr] = o[te][r] * invden[r];
      }
    wave_lds_fence();
    // store: lane = (token lr) x (e-chunk lk4)
    {
      int h = h0 + (lr >> 2), w = w0 + (lr & 3);
      size_t base = ((size_t)(Bg >> 2)) * 4194304 +
                    (size_t)(((Bg & 3) * 2 + (h >> 5))) * 131072 +
                    (size_t)(((h >> 2) & 7)) * 16384 + (size_t)((h & 3) * 64 + w);
#pragma unroll
      for (int ee = 0; ee < 8; ++ee) {
        int e = lk4 * 8 + ee;
        int c = g * 32 + e;
        size_t idx = base + (size_t)(c >> 6) * 1048576 + (size_t)((c >> 3) & 7) * 2048 +
                     (size_t)(c & 7) * 256;
        out[idx] = olw[lr * 33 + e];
      }
    }
    wave_lds_fence();  // protect per-wave buffer reuse across g iterations
  }
}

extern "C" void kernel_launch(void* const* d_in, const int* in_sizes, int n_in,
                              void* d_out, int out_size, void* d_ws, size_t ws_size,
                              hipStream_t stream) {
  const float* x = (const float*)d_in[0];
  const float* qkv_w = (const float*)d_in[1];
  const float* qkv_b = (const float*)d_in[2];
  const float* t0 = (const float*)d_in[3];
  const float* t1 = (const float*)d_in[4];
  float* out = (float*)d_out;
  char* ws = (char*)d_ws;

  u16* qkv = (u16*)ws;                          // 65536*768*2      = 100663296 B
  u16* wb = (u16*)(ws + 100663296);             // 768*256*2        = 393216 B
  float* bias8 = (float*)(ws + 101056512);      // 4*64*64*4        = 65536 B
  float* bias4 = (float*)(ws + 101122048);      // 4*16*16*4        = 4096 B

  k_prep<<<256, 256, 0, stream>>>(qkv_w, t0, t1, wb, bias4, bias8);
  k_gemm<<<1024, 256, 0, stream>>>(x, wb, qkv_b, qkv);
  k_attn8<<<1024, 256, 0, stream>>>(qkv, bias8, out);
  k_attn4<<<1024, 256, 0, stream>>>(qkv, bias4, out);
}

// Round 5
// 132.011 us; speedup vs baseline: 1.5859x; 1.3168x over previous
//
#include <hip/hip_runtime.h>

typedef unsigned short u16;
typedef unsigned int u32;
typedef __attribute__((ext_vector_type(8))) short short8;   // 8 bf16 (MFMA A/B frag)
typedef __attribute__((ext_vector_type(4))) float f32x4;    // MFMA C/D frag
typedef __attribute__((ext_vector_type(4))) float fvec4;
typedef __attribute__((ext_vector_type(4))) u16 u16x4;

__device__ __forceinline__ u16 f2bf(float f) {
  u32 u = __float_as_uint(f);
  u += 0x7FFFu + ((u >> 16) & 1u);   // RTNE
  return (u16)(u >> 16);
}

// wave-local LDS fence: buffers are per-wave, so a full barrier is overkill.
__device__ __forceinline__ void wave_lds_fence() {
  asm volatile("s_waitcnt lgkmcnt(0)" ::: "memory");
  __builtin_amdgcn_sched_barrier(0);
}

// memory row index of token (Bg,h,w); rows of x / qkv are 256 / 768 elems.
__device__ __forceinline__ int m_of(int Bg, int h, int w) {
  return ((Bg >> 2) << 14) | ((h & 3) << 12) | ((((Bg & 3) << 1) | (h >> 5)) << 9) |
         (((h >> 2) & 7) << 6) | w;
}

__device__ __forceinline__ f32x4 mfma16(short8 a, short8 b, f32x4 c) {
  return __builtin_amdgcn_mfma_f32_16x16x32_bf16(a, b, c, 0, 0, 0);
}

// ---------------- prep: convert W to bf16, materialize bias matrices ----------------
__global__ void k_prep(const float* __restrict__ qkv_w, const float* __restrict__ t0,
                       const float* __restrict__ t1, u16* __restrict__ wb,
                       float* __restrict__ bias4, float* __restrict__ bias8) {
  int tid = blockIdx.x * 256 + threadIdx.x;
  int stride = gridDim.x * 256;
  for (int i = tid; i < 768 * 256; i += stride) wb[i] = f2bf(qkv_w[i]);
  for (int i = tid; i < 4 * 64 * 64; i += stride) {
    int g = i >> 12, n = (i >> 6) & 63, m = i & 63;
    int di = (n >> 3) - (m >> 3) + 7, dj = (n & 7) - (m & 7) + 7;
    bias8[i] = t1[(di * 15 + dj) * 4 + g];
  }
  for (int i = tid; i < 4 * 16 * 16; i += stride) {
    int g = i >> 8, n = (i >> 4) & 15, m = i & 15;
    int di = (n >> 2) - (m >> 2) + 3, dj = (n & 3) - (m & 3) + 3;
    bias4[i] = t0[(di * 7 + dj) * 4 + g];
  }
}

// ---------------- QKV GEMM: [65536 x 256] x [256 x 768] -> bf16 qkv[m][768] ----------------
// Block = 64 rows x full 768 cols (x read ONCE). Inner loop is LDS-only: A staged once,
// B staged per-BK=32-chunk (reg-staged: next chunk's loads issue before current compute,
// T14). Swapped mfma(b,a): acc reg-dim = output col -> 8B packed stores.
__global__ __launch_bounds__(512, 2) void k_gemm(const float* __restrict__ x,
                                                 const u16* __restrict__ wb,
                                                 const float* __restrict__ qkv_b,
                                                 u16* __restrict__ qkv) {
  __shared__ __align__(16) u16 As[64 * 264];    // 33792 B, row stride 528B (2-way banks)
  __shared__ __align__(16) u16 Bs[768 * 40];    // 61440 B, row stride 80B (16B-aligned, ~2-way)
  const int t = threadIdx.x;
  const int wid = t >> 6, l = t & 63;
  const int lr = l & 15, lk4 = l >> 4;
  const size_t xbase = (size_t)blockIdx.x * 64 * 256;

  // ---- stage A: fully-coalesced f32 reads (1KB/wave-instr), bf16 LDS writes ----
  {
    const float* xp = x + xbase + (size_t)wid * 256 + (l & 63) * 4;
    const int c = (t & 63) * 4;
#pragma unroll
    for (int it = 0; it < 8; ++it) {
      fvec4 v = *(const fvec4*)(xp + it * 8 * 256);
      int r = wid + it * 8;
      u16x4 u;
      u[0] = f2bf(v[0]); u[1] = f2bf(v[1]); u[2] = f2bf(v[2]); u[3] = f2bf(v[3]);
      *(u16x4*)&As[r * 264 + c] = u;
    }
  }

  // ---- B staging indices: thread covers 6 (col,slot) units of each 48KB chunk ----
  int bcol[6], bslot[6];
#pragma unroll
  for (int j = 0; j < 6; ++j) {
    int idx = t + j * 512;            // 0..3071 = 768 cols x 4 slots of 16B
    bcol[j] = idx >> 2;
    bslot[j] = idx & 3;
  }
  // prologue: load chunk 0 into regs
  short8 bstg[6];
#pragma unroll
  for (int j = 0; j < 6; ++j)
    bstg[j] = *(const short8*)(wb + bcol[j] * 256 + 0 + bslot[j] * 8);

  const int c0 = wid * 96;            // wave owns 96 cols x 64 rows
  f32x4 acc[6][4];
  const f32x4 z = {0.f, 0.f, 0.f, 0.f};
#pragma unroll
  for (int jt = 0; jt < 6; ++jt)
#pragma unroll
    for (int rt = 0; rt < 4; ++rt) acc[jt][rt] = z;

  for (int i = 0; i < 8; ++i) {
    const int kk = i * 32;
    __syncthreads();                  // prev compute's Bs reads done (i=0: A-stage sync)
    // write staged chunk i
#pragma unroll
    for (int j = 0; j < 6; ++j)
      *(short8*)&Bs[bcol[j] * 40 + bslot[j] * 8] = bstg[j];
    // issue chunk i+1's global loads now; latency hides under compute below
    if (i < 7) {
#pragma unroll
      for (int j = 0; j < 6; ++j)
        bstg[j] = *(const short8*)(wb + bcol[j] * 256 + kk + 32 + bslot[j] * 8);
    }
    __syncthreads();                  // Bs writes visible to all waves
    // compute: LDS-only critical path
    short8 a[4], b[6];
#pragma unroll
    for (int rt = 0; rt < 4; ++rt)
      a[rt] = *(const short8*)&As[(rt * 16 + lr) * 264 + kk + lk4 * 8];
#pragma unroll
    for (int jt = 0; jt < 6; ++jt)
      b[jt] = *(const short8*)&Bs[(c0 + jt * 16 + lr) * 40 + lk4 * 8];
#pragma unroll
    for (int jt = 0; jt < 6; ++jt)
#pragma unroll
      for (int rt = 0; rt < 4; ++rt)
        acc[jt][rt] = mfma16(b[jt], a[rt], acc[jt][rt]);  // reg-dim = col, lane-dim = row
  }

  // ---- epilogue: + bias, pack 4 consecutive cols -> one 8B store per (jt,rt) ----
  const int rows0 = blockIdx.x * 64;
#pragma unroll
  for (int jt = 0; jt < 6; ++jt) {
    int col0 = c0 + jt * 16 + lk4 * 4;
    fvec4 bb = *(const fvec4*)(qkv_b + col0);
#pragma unroll
    for (int rt = 0; rt < 4; ++rt) {
      int row = rows0 + rt * 16 + lr;
      u16x4 u;
#pragma unroll
      for (int r = 0; r < 4; ++r) u[r] = f2bf(acc[jt][rt][r] + bb[r]);
      *(u16x4*)&qkv[(size_t)row * 768 + col0] = u;
    }
  }
}

// ---------------- attention ws=8 (group 1, channels 128..255) ----------------
// block = 1 window (1024 blocks), wave = head; all LDS buffers per-wave -> no barriers
__global__ __launch_bounds__(256) void k_attn8(const u16* __restrict__ qkv,
                                               const float* __restrict__ bias8,
                                               float* __restrict__ out) {
  __shared__ __align__(16) u16 vt[4 * 32 * 72];  // per-wave V^T [e][m] (pad 8)
  __shared__ __align__(16) u16 pl[4 * 64 * 72];  // per-wave P [n][m]; reused as O f32 [64][33]
  int bid = blockIdx.x;
  int Bg = bid >> 6, wi = (bid >> 3) & 7, wj = bid & 7;
  int h0 = wi * 8, w0 = wj * 8;
  int g = threadIdx.x >> 6, l = threadIdx.x & 63;
  int lr = l & 15, lk4 = l >> 4;
  u16* vtg = vt + g * (32 * 72);
  u16* plg = pl + g * (64 * 72);

  // load Q,K fragments straight from global (A-layout: row=l&15, k-chunk=(l>>4)*8)
  short8 aq[4], bk[4];
#pragma unroll
  for (int tn = 0; tn < 4; ++tn) {
    int n = tn * 16 + lr;
    int h = h0 + (n >> 3), w = w0 + (n & 7);
    const u16* row = qkv + (size_t)m_of(Bg, h, w) * 768;
    aq[tn] = *(const short8*)(row + 128 + g * 32 + lk4 * 8);
    bk[tn] = *(const short8*)(row + 384 + g * 32 + lk4 * 8);
  }
  // stage V^T: lane l owns token m=l
  {
    int h = h0 + (l >> 3), w = w0 + (l & 7);
    const u16* vrow = qkv + (size_t)m_of(Bg, h, w) * 768 + 640 + g * 32;
    short8 v0 = *(const short8*)(vrow);
    short8 v1 = *(const short8*)(vrow + 8);
    short8 v2 = *(const short8*)(vrow + 16);
    short8 v3 = *(const short8*)(vrow + 24);
#pragma unroll
    for (int j = 0; j < 8; ++j) {
      vtg[(0 + j) * 72 + l] = (u16)v0[j];
      vtg[(8 + j) * 72 + l] = (u16)v1[j];
      vtg[(16 + j) * 72 + l] = (u16)v2[j];
      vtg[(24 + j) * 72 + l] = (u16)v3[j];
    }
  }
  // S = q k^T  (16 MFMAs)
  f32x4 z = {0.f, 0.f, 0.f, 0.f};
  f32x4 s[4][4];
#pragma unroll
  for (int tn = 0; tn < 4; ++tn)
#pragma unroll
    for (int tm = 0; tm < 4; ++tm) s[tn][tm] = mfma16(aq[tn], bk[tm], z);

  const float scale = 0.17677669529663687f;  // 1/sqrt(32)
#pragma unroll
  for (int tn = 0; tn < 4; ++tn)
#pragma unroll
    for (int tm = 0; tm < 4; ++tm)
#pragma unroll
      for (int r = 0; r < 4; ++r) {
        int n = tn * 16 + lk4 * 4 + r, m = tm * 16 + lr;
        s[tn][tm][r] = s[tn][tm][r] * scale + bias8[(g * 64 + n) * 64 + m];
      }
  // softmax over m (row n lives in 16 lanes sharing l>>4)
  float invden[4][4];
#pragma unroll
  for (int tn = 0; tn < 4; ++tn)
#pragma unroll
    for (int r = 0; r < 4; ++r) {
      float mx = fmaxf(fmaxf(s[tn][0][r], s[tn][1][r]), fmaxf(s[tn][2][r], s[tn][3][r]));
#pragma unroll
      for (int d = 1; d < 16; d <<= 1) mx = fmaxf(mx, __shfl_xor(mx, d));
      float sum = 0.f;
#pragma unroll
      for (int tm = 0; tm < 4; ++tm) {
        float p = __expf(s[tn][tm][r] - mx);
        s[tn][tm][r] = p;
        sum += p;
      }
#pragma unroll
      for (int d = 1; d < 16; d <<= 1) sum += __shfl_xor(sum, d);
      invden[tn][r] = 1.f / sum;
    }
  // P -> LDS (bf16)
#pragma unroll
  for (int tn = 0; tn < 4; ++tn)
#pragma unroll
    for (int tm = 0; tm < 4; ++tm)
#pragma unroll
      for (int r = 0; r < 4; ++r)
        plg[(tn * 16 + lk4 * 4 + r) * 72 + tm * 16 + lr] = f2bf(s[tn][tm][r]);
  wave_lds_fence();
  // O = P V  (16 MFMAs)
  f32x4 o[4][2];
#pragma unroll
  for (int tn = 0; tn < 4; ++tn) { o[tn][0] = z; o[tn][1] = z; }
#pragma unroll
  for (int kc = 0; kc < 2; ++kc) {
    short8 pa[4], vb[2];
#pragma unroll
    for (int tn = 0; tn < 4; ++tn)
      pa[tn] = *(const short8*)&plg[(tn * 16 + lr) * 72 + kc * 32 + lk4 * 8];
#pragma unroll
    for (int te = 0; te < 2; ++te)
      vb[te] = *(const short8*)&vtg[(te * 16 + lr) * 72 + kc * 32 + lk4 * 8];
#pragma unroll
    for (int tn = 0; tn < 4; ++tn)
#pragma unroll
      for (int te = 0; te < 2; ++te) o[tn][te] = mfma16(pa[tn], vb[te], o[tn][te]);
  }
  wave_lds_fence();
  // scale by 1/denom, transpose O through LDS (overlay on plg)
  float* ol = (float*)plg;  // [64][33]
#pragma unroll
  for (int tn = 0; tn < 4; ++tn)
#pragma unroll
    for (int te = 0; te < 2; ++te)
#pragma unroll
      for (int r = 0; r < 4; ++r) {
        int n = tn * 16 + lk4 * 4 + r;
        ol[n * 33 + te * 16 + lr] = o[tn][te][r] * invden[tn][r];
      }
  wave_lds_fence();
  // store: lane = token, loop e -> 32B-chunk coalesced runs along w
  {
    int h = h0 + (l >> 3), w = w0 + (l & 7);
    size_t base = ((size_t)(Bg >> 2)) * 4194304 + (size_t)(((Bg & 3) * 2 + (h >> 5))) * 131072 +
                  (size_t)(((h >> 2) & 7)) * 16384 + (size_t)((h & 3) * 64 + w);
#pragma unroll
    for (int e = 0; e < 32; ++e) {
      int c = 128 + g * 32 + e;
      size_t idx = base + (size_t)(c >> 6) * 1048576 + (size_t)((c >> 3) & 7) * 2048 +
                   (size_t)(c & 7) * 256;
      out[idx] = ol[l * 33 + e];
    }
  }
}

// ---------------- attention ws=4 (group 0, channels 0..127) ----------------
// block = 4 windows (1024 blocks), wave = window, heads looped; per-wave buffers -> no barriers
__global__ __launch_bounds__(256) void k_attn4(const u16* __restrict__ qkv,
                                               const float* __restrict__ bias4,
                                               float* __restrict__ out) {
  __shared__ __align__(16) u16 vt[4 * 32 * 40];   // per-wave V^T [e][m0..32] (m 16..31 zero)
  __shared__ __align__(16) u16 pl[4 * 16 * 40];   // per-wave P [n][m0..32] (m 16..31 zero)
  __shared__ __align__(16) float ol[4 * 16 * 33]; // per-wave O
  int wv = threadIdx.x >> 6, l = threadIdx.x & 63;
  int wid = blockIdx.x * 4 + wv;
  int Bg = wid >> 8, wi = (wid >> 4) & 15, wj = wid & 15;
  int h0 = wi * 4, w0 = wj * 4;
  int lr = l & 15, lk4 = l >> 4;
  u16* vtw = vt + wv * (32 * 40);
  u16* plw = pl + wv * (16 * 40);
  float* olw = ol + wv * (16 * 33);
  f32x4 z = {0.f, 0.f, 0.f, 0.f};
  short8 z8 = {0, 0, 0, 0, 0, 0, 0, 0};
  const float scale = 0.17677669529663687f;

  // per-lane token addresses
  int hq = h0 + (lr >> 2), wq = w0 + (lr & 3);
  const u16* rowq = qkv + (size_t)m_of(Bg, hq, wq) * 768;

  for (int g = 0; g < 4; ++g) {
    short8 aq = *(const short8*)(rowq + g * 32 + lk4 * 8);
    short8 bk = *(const short8*)(rowq + 256 + g * 32 + lk4 * 8);
    // stage V^T: lane = (token lr) x (e-chunk lk4)
    {
      short8 v = *(const short8*)(rowq + 512 + g * 32 + lk4 * 8);
#pragma unroll
      for (int j = 0; j < 8; ++j) vtw[(lk4 * 8 + j) * 40 + lr] = (u16)v[j];
      // zero pad m in [16,32)
      *(short8*)&vtw[(l >> 1) * 40 + 16 + (l & 1) * 8] = z8;
    }
    // S (1 MFMA), C rows n = lk4*4+r, cols m = lr
    f32x4 s = mfma16(aq, bk, z);
#pragma unroll
    for (int r = 0; r < 4; ++r) {
      int n = lk4 * 4 + r;
      s[r] = s[r] * scale + bias4[(g * 16 + n) * 16 + lr];
    }
    float invden[4];
#pragma unroll
    for (int r = 0; r < 4; ++r) {
      float mx = s[r];
#pragma unroll
      for (int d = 1; d < 16; d <<= 1) mx = fmaxf(mx, __shfl_xor(mx, d));
      float p = __expf(s[r] - mx);
      s[r] = p;
      float sum = p;
#pragma unroll
      for (int d = 1; d < 16; d <<= 1) sum += __shfl_xor(sum, d);
      invden[r] = 1.f / sum;
    }
    // P -> LDS + zero pad
#pragma unroll
    for (int r = 0; r < 4; ++r) plw[(lk4 * 4 + r) * 40 + lr] = f2bf(s[r]);
    *(u16x4*)&plw[lr * 40 + 16 + lk4 * 4] = (u16x4){0, 0, 0, 0};
    wave_lds_fence();
    // O = P V : 2 MFMAs (te halves), K zero-padded to 32
    f32x4 o[2];
#pragma unroll
    for (int te = 0; te < 2; ++te) {
      short8 pa = *(const short8*)&plw[lr * 40 + lk4 * 8];
      short8 vb = *(const short8*)&vtw[(te * 16 + lr) * 40 + lk4 * 8];
      o[te] = mfma16(pa, vb, z);
    }
#pragma unroll
    for (int te = 0; te < 2; ++te)
#pragma unroll
      for (int r = 0; r < 4; ++r) {
        int n = lk4 * 4 + r;
        olw[n * 33 + te * 16 + lr] = o[te][r] * invden[r];
      }
    wave_lds_fence();
    // store: lane = (token lr) x (e-chunk lk4)
    {
      int h = h0 + (lr >> 2), w = w0 + (lr & 3);
      size_t base = ((size_t)(Bg >> 2)) * 4194304 +
                    (size_t)(((Bg & 3) * 2 + (h >> 5))) * 131072 +
                    (size_t)(((h >> 2) & 7)) * 16384 + (size_t)((h & 3) * 64 + w);
#pragma unroll
      for (int ee = 0; ee < 8; ++ee) {
        int e = lk4 * 8 + ee;
        int c = g * 32 + e;
        size_t idx = base + (size_t)(c >> 6) * 1048576 + (size_t)((c >> 3) & 7) * 2048 +
                     (size_t)(c & 7) * 256;
        out[idx] = olw[lr * 33 + e];
      }
    }
    wave_lds_fence();  // protect per-wave buffer reuse across g iterations
  }
}

extern "C" void kernel_launch(void* const* d_in, const int* in_sizes, int n_in,
                              void* d_out, int out_size, void* d_ws, size_t ws_size,
                              hipStream_t stream) {
  const float* x = (const float*)d_in[0];
  const float* qkv_w = (const float*)d_in[1];
  const float* qkv_b = (const float*)d_in[2];
  const float* t0 = (const float*)d_in[3];
  const float* t1 = (const float*)d_in[4];
  float* out = (float*)d_out;
  char* ws = (char*)d_ws;

  u16* qkv = (u16*)ws;                          // 65536*768*2      = 100663296 B
  u16* wb = (u16*)(ws + 100663296);             // 768*256*2        = 393216 B
  float* bias8 = (float*)(ws + 101056512);      // 4*64*64*4        = 65536 B
  float* bias4 = (float*)(ws + 101122048);      // 4*16*16*4        = 4096 B

  k_prep<<<256, 256, 0, stream>>>(qkv_w, t0, t1, wb, bias4, bias8);
  k_gemm<<<1024, 512, 0, stream>>>(x, wb, qkv_b, qkv);
  k_attn8<<<1024, 256, 0, stream>>>(qkv, bias8, out);
  k_attn4<<<1024, 256, 0, stream>>>(qkv, bias4, out);
}

// Round 6
// 118.912 us; speedup vs baseline: 1.7607x; 1.1102x over previous
//
#include <hip/hip_runtime.h>

typedef unsigned short u16;
typedef unsigned int u32;
typedef __attribute__((ext_vector_type(8))) short short8;   // 8 bf16 (MFMA A/B frag)
typedef __attribute__((ext_vector_type(4))) float f32x4;    // MFMA C/D frag
typedef __attribute__((ext_vector_type(4))) float fvec4;
typedef __attribute__((ext_vector_type(4))) u16 u16x4;

__device__ __forceinline__ u16 f2bf(float f) {
  u32 u = __float_as_uint(f);
  u += 0x7FFFu + ((u >> 16) & 1u);   // RTNE
  return (u16)(u >> 16);
}

// wave-local LDS fence: drains this wave's ds ops only (lgkmcnt), does NOT touch vmcnt
// so global prefetches stay in flight. sched_barrier pins ordering.
__device__ __forceinline__ void wave_lds_fence() {
  asm volatile("s_waitcnt lgkmcnt(0)" ::: "memory");
  __builtin_amdgcn_sched_barrier(0);
}

// memory row index of token (Bg,h,w); rows of x are 256 elems.
__device__ __forceinline__ int m_of(int Bg, int h, int w) {
  return ((Bg >> 2) << 14) | ((h & 3) << 12) | ((((Bg & 3) << 1) | (h >> 5)) << 9) |
         (((h >> 2) & 7) << 6) | w;
}

__device__ __forceinline__ f32x4 mfma16(short8 a, short8 b, f32x4 c) {
  return __builtin_amdgcn_mfma_f32_16x16x32_bf16(a, b, c, 0, 0, 0);
}

// qkvB blocked layout: element (channel c, token m) lives at (c>>2)*262144 + m*4 + (c&3).
// ld8: 8 consecutive channels (c4*4 .. c4*4+7) at token m -> short8 via two 8B loads.
__device__ __forceinline__ short8 ld8(const u16* __restrict__ qb, int c4, int m) {
  union { u16x4 h[2]; short8 v; } u;
  u.h[0] = *(const u16x4*)(qb + (size_t)c4 * 262144 + (size_t)m * 4);
  u.h[1] = *(const u16x4*)(qb + (size_t)(c4 + 1) * 262144 + (size_t)m * 4);
  return u.v;
}

// ---------------- prep: convert W to bf16, materialize bias matrices ----------------
__global__ void k_prep(const float* __restrict__ qkv_w, const float* __restrict__ t0,
                       const float* __restrict__ t1, u16* __restrict__ wb,
                       float* __restrict__ bias4, float* __restrict__ bias8) {
  int tid = blockIdx.x * 256 + threadIdx.x;
  int stride = gridDim.x * 256;
  for (int i = tid; i < 768 * 256; i += stride) wb[i] = f2bf(qkv_w[i]);
  for (int i = tid; i < 4 * 64 * 64; i += stride) {
    int g = i >> 12, n = (i >> 6) & 63, m = i & 63;
    int di = (n >> 3) - (m >> 3) + 7, dj = (n & 7) - (m & 7) + 7;
    bias8[i] = t1[(di * 15 + dj) * 4 + g];
  }
  for (int i = tid; i < 4 * 16 * 16; i += stride) {
    int g = i >> 8, n = (i >> 4) & 15, m = i & 15;
    int di = (n >> 2) - (m >> 2) + 3, dj = (n & 3) - (m & 3) + 3;
    bias4[i] = t0[(di * 7 + dj) * 4 + g];
  }
}

// ---------------- QKV GEMM: [65536 x 256] x [256 x 768] -> qkvB blocked layout ------------
// Block = 64 rows x full 768 cols (x read ONCE), 8 waves. A staged in shared LDS once
// (single barrier). B staged PER-WAVE (6KB slab, XOR-swizzled slots) -> no barriers in the
// K-loop; wave-local lgkmcnt fence only, so B-prefetch vmcnt stays in flight (T14).
__global__ __launch_bounds__(512, 2) void k_gemm(const float* __restrict__ x,
                                                 const u16* __restrict__ wb,
                                                 const float* __restrict__ qkv_b,
                                                 u16* __restrict__ qkvB) {
  __shared__ __align__(16) u16 As[64 * 264];      // 33792 B, shared
  __shared__ __align__(16) u16 Bs[8 * 96 * 32];   // 49152 B, per-wave slabs of 96x32
  const int t = threadIdx.x;
  const int wid = t >> 6, l = t & 63;
  const int lr = l & 15, lk4 = l >> 4;
  const size_t xbase = (size_t)blockIdx.x * 64 * 256;

  // ---- stage A: coalesced f32 reads, bf16 LDS writes (once per block) ----
  {
    const float* xp = x + xbase + (size_t)wid * 256 + (l & 63) * 4;
    const int c = (l & 63) * 4;
#pragma unroll
    for (int it = 0; it < 8; ++it) {
      fvec4 v = *(const fvec4*)(xp + it * 8 * 256);
      int r = wid + it * 8;
      u16x4 u;
      u[0] = f2bf(v[0]); u[1] = f2bf(v[1]); u[2] = f2bf(v[2]); u[3] = f2bf(v[3]);
      *(u16x4*)&As[r * 264 + c] = u;
    }
  }

  // ---- per-wave B staging setup: unit u = l + j*64 -> (col cu = u>>2, slot su = u&3) ----
  const int c0 = wid * 96;                 // wave owns cols c0..c0+95 (all 64 rows)
  const int wvb = wid * (96 * 32);         // per-wave Bs base (u16 units)
  int goff[6], loff[6];
#pragma unroll
  for (int j = 0; j < 6; ++j) {
    int u = l + j * 64;
    int cu = u >> 2, su = u & 3;
    goff[j] = (c0 + cu) * 256 + su * 8;                      // global (u16 units)
    loff[j] = wvb + cu * 32 + ((su ^ ((cu >> 1) & 3)) * 8);  // swizzled LDS addr
  }
  // prologue: load chunk 0
  short8 bstg[6];
#pragma unroll
  for (int j = 0; j < 6; ++j) bstg[j] = *(const short8*)(wb + goff[j]);

  f32x4 acc[6][4];
  const f32x4 z = {0.f, 0.f, 0.f, 0.f};
#pragma unroll
  for (int jt = 0; jt < 6; ++jt)
#pragma unroll
    for (int rt = 0; rt < 4; ++rt) acc[jt][rt] = z;

  __syncthreads();  // As visible (the only barrier)

  const int bswz = (lr >> 1) & 3;          // B-read slot swizzle (row = jt*16+lr)
#pragma unroll
  for (int i = 0; i < 8; ++i) {
    const int kk = i * 32;
    // write staged chunk i into this wave's slab (compiler inserts vmcnt for bstg)
#pragma unroll
    for (int j = 0; j < 6; ++j) *(short8*)&Bs[loff[j]] = bstg[j];
    // issue chunk i+1's global loads now; they stay in flight under the MFMAs below
    if (i < 7) {
#pragma unroll
      for (int j = 0; j < 6; ++j) bstg[j] = *(const short8*)(wb + goff[j] + kk + 32);
    }
    wave_lds_fence();  // write->read visibility, wave-local only
    short8 a[4], b[6];
#pragma unroll
    for (int rt = 0; rt < 4; ++rt)
      a[rt] = *(const short8*)&As[(rt * 16 + lr) * 264 + kk + lk4 * 8];
#pragma unroll
    for (int jt = 0; jt < 6; ++jt)
      b[jt] = *(const short8*)&Bs[wvb + (jt * 16 + lr) * 32 + ((lk4 ^ bswz) * 8)];
#pragma unroll
    for (int jt = 0; jt < 6; ++jt)
#pragma unroll
      for (int rt = 0; rt < 4; ++rt)
        acc[jt][rt] = mfma16(b[jt], a[rt], acc[jt][rt]);  // reg-dim = col, lane-dim = row
  }

  // ---- epilogue: + bias, blocked layout -> per-lane u16x4, 512B/instr coalesced ----
  const int rows0 = blockIdx.x * 64;
#pragma unroll
  for (int jt = 0; jt < 6; ++jt) {
    int col0 = c0 + jt * 16 + lk4 * 4;
    fvec4 bb = *(const fvec4*)(qkv_b + col0);
    int c40 = col0 >> 2;
#pragma unroll
    for (int rt = 0; rt < 4; ++rt) {
      int row = rows0 + rt * 16 + lr;
      u16x4 u;
#pragma unroll
      for (int r = 0; r < 4; ++r) u[r] = f2bf(acc[jt][rt][r] + bb[r]);
      *(u16x4*)&qkvB[(size_t)c40 * 262144 + (size_t)row * 4] = u;
    }
  }
}

// ---------------- attention ws=8 (group 1, channels 128..255) ----------------
// block = 1 window (1024 blocks), wave = head; all LDS buffers per-wave -> no barriers
__global__ __launch_bounds__(256) void k_attn8(const u16* __restrict__ qkvB,
                                               const float* __restrict__ bias8,
                                               float* __restrict__ out) {
  __shared__ __align__(16) u16 vt[4 * 32 * 72];  // per-wave V^T [e][m] (pad 8)
  __shared__ __align__(16) u16 pl[4 * 64 * 72];  // per-wave P [n][m]; reused as O f32 [64][33]
  int bid = blockIdx.x;
  int Bg = bid >> 6, wi = (bid >> 3) & 7, wj = bid & 7;
  int h0 = wi * 8, w0 = wj * 8;
  int g = threadIdx.x >> 6, l = threadIdx.x & 63;
  int lr = l & 15, lk4 = l >> 4;
  u16* vtg = vt + g * (32 * 72);
  u16* plg = pl + g * (64 * 72);

  // load Q,K fragments straight from global (A-layout: row=l&15, k-chunk=(l>>4)*8)
  const int c4q = 32 + g * 8 + lk4 * 2;   // q chans 128+g*32+lk4*8
  const int c4k = 96 + g * 8 + lk4 * 2;   // k chans 384+g*32+lk4*8
  short8 aq[4], bk[4];
#pragma unroll
  for (int tn = 0; tn < 4; ++tn) {
    int n = tn * 16 + lr;
    int m = m_of(Bg, h0 + (n >> 3), w0 + (n & 7));
    aq[tn] = ld8(qkvB, c4q, m);
    bk[tn] = ld8(qkvB, c4k, m);
  }
  // stage V^T: lane l owns token m=l; v chans 640+g*32 .. +31 (8 c4-groups)
  {
    int m = m_of(Bg, h0 + (l >> 3), w0 + (l & 7));
#pragma unroll
    for (int j2 = 0; j2 < 8; ++j2) {
      u16x4 p = *(const u16x4*)(qkvB + (size_t)(160 + g * 8 + j2) * 262144 + (size_t)m * 4);
#pragma unroll
      for (int r = 0; r < 4; ++r) vtg[(j2 * 4 + r) * 72 + l] = p[r];
    }
  }
  // S = q k^T  (16 MFMAs)
  f32x4 z = {0.f, 0.f, 0.f, 0.f};
  f32x4 s[4][4];
#pragma unroll
  for (int tn = 0; tn < 4; ++tn)
#pragma unroll
    for (int tm = 0; tm < 4; ++tm) s[tn][tm] = mfma16(aq[tn], bk[tm], z);

  const float scale = 0.17677669529663687f;  // 1/sqrt(32)
#pragma unroll
  for (int tn = 0; tn < 4; ++tn)
#pragma unroll
    for (int tm = 0; tm < 4; ++tm)
#pragma unroll
      for (int r = 0; r < 4; ++r) {
        int n = tn * 16 + lk4 * 4 + r, m = tm * 16 + lr;
        s[tn][tm][r] = s[tn][tm][r] * scale + bias8[(g * 64 + n) * 64 + m];
      }
  // softmax over m (row n lives in 16 lanes sharing l>>4)
  float invden[4][4];
#pragma unroll
  for (int tn = 0; tn < 4; ++tn)
#pragma unroll
    for (int r = 0; r < 4; ++r) {
      float mx = fmaxf(fmaxf(s[tn][0][r], s[tn][1][r]), fmaxf(s[tn][2][r], s[tn][3][r]));
#pragma unroll
      for (int d = 1; d < 16; d <<= 1) mx = fmaxf(mx, __shfl_xor(mx, d));
      float sum = 0.f;
#pragma unroll
      for (int tm = 0; tm < 4; ++tm) {
        float p = __expf(s[tn][tm][r] - mx);
        s[tn][tm][r] = p;
        sum += p;
      }
#pragma unroll
      for (int d = 1; d < 16; d <<= 1) sum += __shfl_xor(sum, d);
      invden[tn][r] = 1.f / sum;
    }
  // P -> LDS (bf16)
#pragma unroll
  for (int tn = 0; tn < 4; ++tn)
#pragma unroll
    for (int tm = 0; tm < 4; ++tm)
#pragma unroll
      for (int r = 0; r < 4; ++r)
        plg[(tn * 16 + lk4 * 4 + r) * 72 + tm * 16 + lr] = f2bf(s[tn][tm][r]);
  wave_lds_fence();
  // O = P V  (16 MFMAs)
  f32x4 o[4][2];
#pragma unroll
  for (int tn = 0; tn < 4; ++tn) { o[tn][0] = z; o[tn][1] = z; }
#pragma unroll
  for (int kc = 0; kc < 2; ++kc) {
    short8 pa[4], vb[2];
#pragma unroll
    for (int tn = 0; tn < 4; ++tn)
      pa[tn] = *(const short8*)&plg[(tn * 16 + lr) * 72 + kc * 32 + lk4 * 8];
#pragma unroll
    for (int te = 0; te < 2; ++te)
      vb[te] = *(const short8*)&vtg[(te * 16 + lr) * 72 + kc * 32 + lk4 * 8];
#pragma unroll
    for (int tn = 0; tn < 4; ++tn)
#pragma unroll
      for (int te = 0; te < 2; ++te) o[tn][te] = mfma16(pa[tn], vb[te], o[tn][te]);
  }
  wave_lds_fence();
  // scale by 1/denom, transpose O through LDS (overlay on plg)
  float* ol = (float*)plg;  // [64][33]
#pragma unroll
  for (int tn = 0; tn < 4; ++tn)
#pragma unroll
    for (int te = 0; te < 2; ++te)
#pragma unroll
      for (int r = 0; r < 4; ++r) {
        int n = tn * 16 + lk4 * 4 + r;
        ol[n * 33 + te * 16 + lr] = o[tn][te][r] * invden[tn][r];
      }
  wave_lds_fence();
  // store: lane = token, loop e -> 32B-chunk coalesced runs along w
  {
    int h = h0 + (l >> 3), w = w0 + (l & 7);
    size_t base = ((size_t)(Bg >> 2)) * 4194304 + (size_t)(((Bg & 3) * 2 + (h >> 5))) * 131072 +
                  (size_t)(((h >> 2) & 7)) * 16384 + (size_t)((h & 3) * 64 + w);
#pragma unroll
    for (int e = 0; e < 32; ++e) {
      int c = 128 + g * 32 + e;
      size_t idx = base + (size_t)(c >> 6) * 1048576 + (size_t)((c >> 3) & 7) * 2048 +
                   (size_t)(c & 7) * 256;
      out[idx] = ol[l * 33 + e];
    }
  }
}

// ---------------- attention ws=4 (group 0, channels 0..127) ----------------
// block = 4 windows (1024 blocks), wave = window, heads looped; per-wave buffers -> no barriers
__global__ __launch_bounds__(256) void k_attn4(const u16* __restrict__ qkvB,
                                               const float* __restrict__ bias4,
                                               float* __restrict__ out) {
  __shared__ __align__(16) u16 vt[4 * 32 * 40];   // per-wave V^T [e][m0..32] (m 16..31 zero)
  __shared__ __align__(16) u16 pl[4 * 16 * 40];   // per-wave P [n][m0..32] (m 16..31 zero)
  __shared__ __align__(16) float ol[4 * 16 * 33]; // per-wave O
  int wv = threadIdx.x >> 6, l = threadIdx.x & 63;
  int wid = blockIdx.x * 4 + wv;
  int Bg = wid >> 8, wi = (wid >> 4) & 15, wj = wid & 15;
  int h0 = wi * 4, w0 = wj * 4;
  int lr = l & 15, lk4 = l >> 4;
  u16* vtw = vt + wv * (32 * 40);
  u16* plw = pl + wv * (16 * 40);
  float* olw = ol + wv * (16 * 33);
  f32x4 z = {0.f, 0.f, 0.f, 0.f};
  short8 z8 = {0, 0, 0, 0, 0, 0, 0, 0};
  const float scale = 0.17677669529663687f;

  // per-lane token index
  int hq = h0 + (lr >> 2), wq = w0 + (lr & 3);
  const int mq = m_of(Bg, hq, wq);

  for (int g = 0; g < 4; ++g) {
    short8 aq = ld8(qkvB, g * 8 + lk4 * 2, mq);          // q chans g*32+lk4*8
    short8 bk = ld8(qkvB, 64 + g * 8 + lk4 * 2, mq);     // k chans 256+g*32+lk4*8
    // stage V^T: lane = (token lr) x (e-chunk lk4)
    {
      short8 v = ld8(qkvB, 128 + g * 8 + lk4 * 2, mq);   // v chans 512+g*32+lk4*8
#pragma unroll
      for (int j = 0; j < 8; ++j) vtw[(lk4 * 8 + j) * 40 + lr] = (u16)v[j];
      // zero pad m in [16,32)
      *(short8*)&vtw[(l >> 1) * 40 + 16 + (l & 1) * 8] = z8;
    }
    // S (1 MFMA), C rows n = lk4*4+r, cols m = lr
    f32x4 s = mfma16(aq, bk, z);
#pragma unroll
    for (int r = 0; r < 4; ++r) {
      int n = lk4 * 4 + r;
      s[r] = s[r] * scale + bias4[(g * 16 + n) * 16 + lr];
    }
    float invden[4];
#pragma unroll
    for (int r = 0; r < 4; ++r) {
      float mx = s[r];
#pragma unroll
      for (int d = 1; d < 16; d <<= 1) mx = fmaxf(mx, __shfl_xor(mx, d));
      float p = __expf(s[r] - mx);
      s[r] = p;
      float sum = p;
#pragma unroll
      for (int d = 1; d < 16; d <<= 1) sum += __shfl_xor(sum, d);
      invden[r] = 1.f / sum;
    }
    // P -> LDS + zero pad
#pragma unroll
    for (int r = 0; r < 4; ++r) plw[(lk4 * 4 + r) * 40 + lr] = f2bf(s[r]);
    *(u16x4*)&plw[lr * 40 + 16 + lk4 * 4] = (u16x4){0, 0, 0, 0};
    wave_lds_fence();
    // O = P V : 2 MFMAs (te halves), K zero-padded to 32
    f32x4 o[2];
#pragma unroll
    for (int te = 0; te < 2; ++te) {
      short8 pa = *(const short8*)&plw[lr * 40 + lk4 * 8];
      short8 vb = *(const short8*)&vtw[(te * 16 + lr) * 40 + lk4 * 8];
      o[te] = mfma16(pa, vb, z);
    }
#pragma unroll
    for (int te = 0; te < 2; ++te)
#pragma unroll
      for (int r = 0; r < 4; ++r) {
        int n = lk4 * 4 + r;
        olw[n * 33 + te * 16 + lr] = o[te][r] * invden[r];
      }
    wave_lds_fence();
    // store: lane = (token lr) x (e-chunk lk4)
    {
      int h = h0 + (lr >> 2), w = w0 + (lr & 3);
      size_t base = ((size_t)(Bg >> 2)) * 4194304 +
                    (size_t)(((Bg & 3) * 2 + (h >> 5))) * 131072 +
                    (size_t)(((h >> 2) & 7)) * 16384 + (size_t)((h & 3) * 64 + w);
#pragma unroll
      for (int ee = 0; ee < 8; ++ee) {
        int e = lk4 * 8 + ee;
        int c = g * 32 + e;
        size_t idx = base + (size_t)(c >> 6) * 1048576 + (size_t)((c >> 3) & 7) * 2048 +
                     (size_t)(c & 7) * 256;
        out[idx] = olw[lr * 33 + e];
      }
    }
    wave_lds_fence();  // protect per-wave buffer reuse across g iterations
  }
}

extern "C" void kernel_launch(void* const* d_in, const int* in_sizes, int n_in,
                              void* d_out, int out_size, void* d_ws, size_t ws_size,
                              hipStream_t stream) {
  const float* x = (const float*)d_in[0];
  const float* qkv_w = (const float*)d_in[1];
  const float* qkv_b = (const float*)d_in[2];
  const float* t0 = (const float*)d_in[3];
  const float* t1 = (const float*)d_in[4];
  float* out = (float*)d_out;
  char* ws = (char*)d_ws;

  u16* qkvB = (u16*)ws;                         // 192*65536*4 u16  = 100663296 B
  u16* wb = (u16*)(ws + 100663296);             // 768*256*2        = 393216 B
  float* bias8 = (float*)(ws + 101056512);      // 4*64*64*4        = 65536 B
  float* bias4 = (float*)(ws + 101122048);      // 4*16*16*4        = 4096 B

  k_prep<<<256, 256, 0, stream>>>(qkv_w, t0, t1, wb, bias4, bias8);
  k_gemm<<<1024, 512, 0, stream>>>(x, wb, qkv_b, qkvB);
  k_attn8<<<1024, 256, 0, stream>>>(qkvB, bias8, out);
  k_attn4<<<1024, 256, 0, stream>>>(qkvB, bias4, out);
}

// Round 7
// 116.435 us; speedup vs baseline: 1.7981x; 1.0213x over previous
//
#include <hip/hip_runtime.h>

typedef unsigned short u16;
typedef unsigned int u32;
typedef __attribute__((ext_vector_type(8))) short short8;   // 8 bf16 (MFMA A/B frag)
typedef __attribute__((ext_vector_type(4))) float f32x4;    // MFMA C/D frag
typedef __attribute__((ext_vector_type(4))) float fvec4;
typedef __attribute__((ext_vector_type(4))) u16 u16x4;

__device__ __forceinline__ u16 f2bf(float f) {
  u32 u = __float_as_uint(f);
  u += 0x7FFFu + ((u >> 16) & 1u);   // RTNE
  return (u16)(u >> 16);
}

// wave-local LDS fence: drains this wave's ds ops only (lgkmcnt), does NOT touch vmcnt
// so global prefetches stay in flight. sched_barrier pins ordering.
__device__ __forceinline__ void wave_lds_fence() {
  asm volatile("s_waitcnt lgkmcnt(0)" ::: "memory");
  __builtin_amdgcn_sched_barrier(0);
}

// memory row index of token (Bg,h,w); rows of x are 256 elems.
__device__ __forceinline__ int m_of(int Bg, int h, int w) {
  return ((Bg >> 2) << 14) | ((h & 3) << 12) | ((((Bg & 3) << 1) | (h >> 5)) << 9) |
         (((h >> 2) & 7) << 6) | w;
}

__device__ __forceinline__ f32x4 mfma16(short8 a, short8 b, f32x4 c) {
  return __builtin_amdgcn_mfma_f32_16x16x32_bf16(a, b, c, 0, 0, 0);
}

// qkvB blocked layout: element (channel c, token m) lives at (c>>2)*262144 + m*4 + (c&3).
// ld8: 8 consecutive channels (c4*4 .. c4*4+7) at token m -> short8 via two 8B loads.
__device__ __forceinline__ short8 ld8(const u16* __restrict__ qb, int c4, int m) {
  union { u16x4 h[2]; short8 v; } u;
  u.h[0] = *(const u16x4*)(qb + (size_t)c4 * 262144 + (size_t)m * 4);
  u.h[1] = *(const u16x4*)(qb + (size_t)(c4 + 1) * 262144 + (size_t)m * 4);
  return u.v;
}

// ---------------- prep: convert W to bf16, materialize bias matrices ----------------
__global__ void k_prep(const float* __restrict__ qkv_w, const float* __restrict__ t0,
                       const float* __restrict__ t1, u16* __restrict__ wb,
                       float* __restrict__ bias4, float* __restrict__ bias8) {
  int tid = blockIdx.x * 256 + threadIdx.x;
  int stride = gridDim.x * 256;
  for (int i = tid; i < 768 * 256; i += stride) wb[i] = f2bf(qkv_w[i]);
  for (int i = tid; i < 4 * 64 * 64; i += stride) {
    int g = i >> 12, n = (i >> 6) & 63, m = i & 63;
    int di = (n >> 3) - (m >> 3) + 7, dj = (n & 7) - (m & 7) + 7;
    bias8[i] = t1[(di * 15 + dj) * 4 + g];
  }
  for (int i = tid; i < 4 * 16 * 16; i += stride) {
    int g = i >> 8, n = (i >> 4) & 15, m = i & 15;
    int di = (n >> 2) - (m >> 2) + 3, dj = (n & 3) - (m & 3) + 3;
    bias4[i] = t0[(di * 7 + dj) * 4 + g];
  }
}

// ---------------- QKV GEMM: [65536 x 256] x [256 x 768] -> qkvB blocked layout ------------
// Block = 64 rows x full 768 cols (x read ONCE), 8 waves. A staged in shared LDS once
// (single barrier). B: per-wave DOUBLE-BUFFERED 6KB slabs (XOR-swizzled). Per iter:
// fence(old) -> read chunk i (buf i&1) -> write chunk i+1 (buf i^1; vmcnt waits on loads
// issued one iter ago) -> prefetch chunk i+2 -> MFMAs. No same-iter dependencies.
__global__ __launch_bounds__(512, 2) void k_gemm(const float* __restrict__ x,
                                                 const u16* __restrict__ wb,
                                                 const float* __restrict__ qkv_b,
                                                 u16* __restrict__ qkvB) {
  __shared__ __align__(16) u16 As[64 * 264];        // 33792 B, shared
  __shared__ __align__(16) u16 Bs[2 * 8 * 96 * 32]; // 98304 B: 2 bufs x 8 waves x 96x32
  const int t = threadIdx.x;
  const int wid = t >> 6, l = t & 63;
  const int lr = l & 15, lk4 = l >> 4;
  const size_t xbase = (size_t)blockIdx.x * 64 * 256;

  const int c0 = wid * 96;                 // wave owns cols c0..c0+95 (all 64 rows)
  const int wvb = wid * 3072;              // per-wave slab base (u16 units)
  int goff[6], loff[6];
#pragma unroll
  for (int j = 0; j < 6; ++j) {
    int u = l + j * 64;
    int cu = u >> 2, su = u & 3;
    goff[j] = (c0 + cu) * 256 + su * 8;                      // global (u16 units)
    loff[j] = wvb + cu * 32 + ((su ^ ((cu >> 1) & 3)) * 8);  // swizzled LDS addr
  }

  // ---- prologue: issue chunk0+chunk1 B loads FIRST (barrier drain will cover them) ----
  short8 bstg0[6], bstg[6];
#pragma unroll
  for (int j = 0; j < 6; ++j) bstg0[j] = *(const short8*)(wb + goff[j]);
#pragma unroll
  for (int j = 0; j < 6; ++j) bstg[j] = *(const short8*)(wb + goff[j] + 32);

  // ---- stage A: coalesced f32 reads, bf16 LDS writes (once per block) ----
  {
    const float* xp = x + xbase + (size_t)wid * 256 + (l & 63) * 4;
    const int c = (l & 63) * 4;
#pragma unroll
    for (int it = 0; it < 8; ++it) {
      fvec4 v = *(const fvec4*)(xp + it * 8 * 256);
      int r = wid + it * 8;
      u16x4 u;
      u[0] = f2bf(v[0]); u[1] = f2bf(v[1]); u[2] = f2bf(v[2]); u[3] = f2bf(v[3]);
      *(u16x4*)&As[r * 264 + c] = u;
    }
  }
  // write chunk 0 into buf 0 (vmcnt wait only counts back to bstg0's loads)
#pragma unroll
  for (int j = 0; j < 6; ++j) *(short8*)&Bs[loff[j]] = bstg0[j];

  f32x4 acc[6][4];
  const f32x4 z = {0.f, 0.f, 0.f, 0.f};
#pragma unroll
  for (int jt = 0; jt < 6; ++jt)
#pragma unroll
    for (int rt = 0; rt < 4; ++rt) acc[jt][rt] = z;

  __syncthreads();  // As + buf0 visible; drains chunk-1 prefetch too (once per block)

  const int bswz = (lr >> 1) & 3;          // B-read slot swizzle (row = jt*16+lr)
#pragma unroll
  for (int i = 0; i < 8; ++i) {
    const int kk = i * 32;
    const int cb = (i & 1) * 24576;        // current buf (u16 units)
    const int nb = 24576 - cb;             // next buf
    // old writes (issued one iter ago) are long done; this is ~free
    wave_lds_fence();
    // reads of chunk i
    short8 a[4], b[6];
#pragma unroll
    for (int rt = 0; rt < 4; ++rt)
      a[rt] = *(const short8*)&As[(rt * 16 + lr) * 264 + kk + lk4 * 8];
#pragma unroll
    for (int jt = 0; jt < 6; ++jt)
      b[jt] = *(const short8*)&Bs[cb + wvb + (jt * 16 + lr) * 32 + ((lk4 ^ bswz) * 8)];
    // write chunk i+1 into the other buffer (vmcnt waits on loads issued last iter)
    if (i < 7) {
#pragma unroll
      for (int j = 0; j < 6; ++j) *(short8*)&Bs[nb + loff[j]] = bstg[j];
    }
    // prefetch chunk i+2; stays in flight under the MFMAs below
    if (i < 6) {
#pragma unroll
      for (int j = 0; j < 6; ++j) bstg[j] = *(const short8*)(wb + goff[j] + kk + 64);
    }
    __builtin_amdgcn_sched_barrier(0);     // pin loads/writes before the MFMA block
#pragma unroll
    for (int jt = 0; jt < 6; ++jt)
#pragma unroll
      for (int rt = 0; rt < 4; ++rt)
        acc[jt][rt] = mfma16(b[jt], a[rt], acc[jt][rt]);  // reg-dim = col, lane-dim = row
  }

  // ---- epilogue: + bias, blocked layout -> per-lane u16x4, 512B/instr coalesced ----
  const int rows0 = blockIdx.x * 64;
#pragma unroll
  for (int jt = 0; jt < 6; ++jt) {
    int col0 = c0 + jt * 16 + lk4 * 4;
    fvec4 bb = *(const fvec4*)(qkv_b + col0);
    int c40 = col0 >> 2;
#pragma unroll
    for (int rt = 0; rt < 4; ++rt) {
      int row = rows0 + rt * 16 + lr;
      u16x4 u;
#pragma unroll
      for (int r = 0; r < 4; ++r) u[r] = f2bf(acc[jt][rt][r] + bb[r]);
      *(u16x4*)&qkvB[(size_t)c40 * 262144 + (size_t)row * 4] = u;
    }
  }
}

// ---------------- attention ws=8 (group 1, channels 128..255) ----------------
// block = 1 window (1024 blocks), wave = head; all LDS buffers per-wave -> no barriers
__global__ __launch_bounds__(256) void k_attn8(const u16* __restrict__ qkvB,
                                               const float* __restrict__ bias8,
                                               float* __restrict__ out) {
  __shared__ __align__(16) u16 vt[4 * 32 * 72];  // per-wave V^T [e][m] (pad 8)
  __shared__ __align__(16) u16 pl[4 * 64 * 72];  // per-wave P [n][m]; reused as O f32 [64][33]
  int bid = blockIdx.x;
  int Bg = bid >> 6, wi = (bid >> 3) & 7, wj = bid & 7;
  int h0 = wi * 8, w0 = wj * 8;
  int g = threadIdx.x >> 6, l = threadIdx.x & 63;
  int lr = l & 15, lk4 = l >> 4;
  u16* vtg = vt + g * (32 * 72);
  u16* plg = pl + g * (64 * 72);

  // load Q,K fragments straight from global (A-layout: row=l&15, k-chunk=(l>>4)*8)
  const int c4q = 32 + g * 8 + lk4 * 2;   // q chans 128+g*32+lk4*8
  const int c4k = 96 + g * 8 + lk4 * 2;   // k chans 384+g*32+lk4*8
  short8 aq[4], bk[4];
#pragma unroll
  for (int tn = 0; tn < 4; ++tn) {
    int n = tn * 16 + lr;
    int m = m_of(Bg, h0 + (n >> 3), w0 + (n & 7));
    aq[tn] = ld8(qkvB, c4q, m);
    bk[tn] = ld8(qkvB, c4k, m);
  }
  // stage V^T: lane l owns token m=l; v chans 640+g*32 .. +31 (8 c4-groups)
  {
    int m = m_of(Bg, h0 + (l >> 3), w0 + (l & 7));
#pragma unroll
    for (int j2 = 0; j2 < 8; ++j2) {
      u16x4 p = *(const u16x4*)(qkvB + (size_t)(160 + g * 8 + j2) * 262144 + (size_t)m * 4);
#pragma unroll
      for (int r = 0; r < 4; ++r) vtg[(j2 * 4 + r) * 72 + l] = p[r];
    }
  }
  // S = q k^T  (16 MFMAs)
  f32x4 z = {0.f, 0.f, 0.f, 0.f};
  f32x4 s[4][4];
#pragma unroll
  for (int tn = 0; tn < 4; ++tn)
#pragma unroll
    for (int tm = 0; tm < 4; ++tm) s[tn][tm] = mfma16(aq[tn], bk[tm], z);

  const float scale = 0.17677669529663687f;  // 1/sqrt(32)
#pragma unroll
  for (int tn = 0; tn < 4; ++tn)
#pragma unroll
    for (int tm = 0; tm < 4; ++tm)
#pragma unroll
      for (int r = 0; r < 4; ++r) {
        int n = tn * 16 + lk4 * 4 + r, m = tm * 16 + lr;
        s[tn][tm][r] = s[tn][tm][r] * scale + bias8[(g * 64 + n) * 64 + m];
      }
  // softmax over m (row n lives in 16 lanes sharing l>>4)
  float invden[4][4];
#pragma unroll
  for (int tn = 0; tn < 4; ++tn)
#pragma unroll
    for (int r = 0; r < 4; ++r) {
      float mx = fmaxf(fmaxf(s[tn][0][r], s[tn][1][r]), fmaxf(s[tn][2][r], s[tn][3][r]));
#pragma unroll
      for (int d = 1; d < 16; d <<= 1) mx = fmaxf(mx, __shfl_xor(mx, d));
      float sum = 0.f;
#pragma unroll
      for (int tm = 0; tm < 4; ++tm) {
        float p = __expf(s[tn][tm][r] - mx);
        s[tn][tm][r] = p;
        sum += p;
      }
#pragma unroll
      for (int d = 1; d < 16; d <<= 1) sum += __shfl_xor(sum, d);
      invden[tn][r] = 1.f / sum;
    }
  // P -> LDS (bf16)
#pragma unroll
  for (int tn = 0; tn < 4; ++tn)
#pragma unroll
    for (int tm = 0; tm < 4; ++tm)
#pragma unroll
      for (int r = 0; r < 4; ++r)
        plg[(tn * 16 + lk4 * 4 + r) * 72 + tm * 16 + lr] = f2bf(s[tn][tm][r]);
  wave_lds_fence();
  // O = P V  (16 MFMAs)
  f32x4 o[4][2];
#pragma unroll
  for (int tn = 0; tn < 4; ++tn) { o[tn][0] = z; o[tn][1] = z; }
#pragma unroll
  for (int kc = 0; kc < 2; ++kc) {
    short8 pa[4], vb[2];
#pragma unroll
    for (int tn = 0; tn < 4; ++tn)
      pa[tn] = *(const short8*)&plg[(tn * 16 + lr) * 72 + kc * 32 + lk4 * 8];
#pragma unroll
    for (int te = 0; te < 2; ++te)
      vb[te] = *(const short8*)&vtg[(te * 16 + lr) * 72 + kc * 32 + lk4 * 8];
#pragma unroll
    for (int tn = 0; tn < 4; ++tn)
#pragma unroll
      for (int te = 0; te < 2; ++te) o[tn][te] = mfma16(pa[tn], vb[te], o[tn][te]);
  }
  wave_lds_fence();
  // scale by 1/denom, transpose O through LDS (overlay on plg)
  float* ol = (float*)plg;  // [64][33]
#pragma unroll
  for (int tn = 0; tn < 4; ++tn)
#pragma unroll
    for (int te = 0; te < 2; ++te)
#pragma unroll
      for (int r = 0; r < 4; ++r) {
        int n = tn * 16 + lk4 * 4 + r;
        ol[n * 33 + te * 16 + lr] = o[tn][te][r] * invden[tn][r];
      }
  wave_lds_fence();
  // store: lane = token, loop e -> 32B-chunk coalesced runs along w
  {
    int h = h0 + (l >> 3), w = w0 + (l & 7);
    size_t base = ((size_t)(Bg >> 2)) * 4194304 + (size_t)(((Bg & 3) * 2 + (h >> 5))) * 131072 +
                  (size_t)(((h >> 2) & 7)) * 16384 + (size_t)((h & 3) * 64 + w);
#pragma unroll
    for (int e = 0; e < 32; ++e) {
      int c = 128 + g * 32 + e;
      size_t idx = base + (size_t)(c >> 6) * 1048576 + (size_t)((c >> 3) & 7) * 2048 +
                   (size_t)(c & 7) * 256;
      out[idx] = ol[l * 33 + e];
    }
  }
}

// ---------------- attention ws=4 (group 0, channels 0..127) ----------------
// block = 4 windows (1024 blocks), wave = window, heads looped; per-wave buffers -> no barriers
__global__ __launch_bounds__(256) void k_attn4(const u16* __restrict__ qkvB,
                                               const float* __restrict__ bias4,
                                               float* __restrict__ out) {
  __shared__ __align__(16) u16 vt[4 * 32 * 40];   // per-wave V^T [e][m0..32] (m 16..31 zero)
  __shared__ __align__(16) u16 pl[4 * 16 * 40];   // per-wave P [n][m0..32] (m 16..31 zero)
  __shared__ __align__(16) float ol[4 * 16 * 33]; // per-wave O
  int wv = threadIdx.x >> 6, l = threadIdx.x & 63;
  int wid = blockIdx.x * 4 + wv;
  int Bg = wid >> 8, wi = (wid >> 4) & 15, wj = wid & 15;
  int h0 = wi * 4, w0 = wj * 4;
  int lr = l & 15, lk4 = l >> 4;
  u16* vtw = vt + wv * (32 * 40);
  u16* plw = pl + wv * (16 * 40);
  float* olw = ol + wv * (16 * 33);
  f32x4 z = {0.f, 0.f, 0.f, 0.f};
  short8 z8 = {0, 0, 0, 0, 0, 0, 0, 0};
  const float scale = 0.17677669529663687f;

  // per-lane token index
  int hq = h0 + (lr >> 2), wq = w0 + (lr & 3);
  const int mq = m_of(Bg, hq, wq);

  for (int g = 0; g < 4; ++g) {
    short8 aq = ld8(qkvB, g * 8 + lk4 * 2, mq);          // q chans g*32+lk4*8
    short8 bk = ld8(qkvB, 64 + g * 8 + lk4 * 2, mq);     // k chans 256+g*32+lk4*8
    // stage V^T: lane = (token lr) x (e-chunk lk4)
    {
      short8 v = ld8(qkvB, 128 + g * 8 + lk4 * 2, mq);   // v chans 512+g*32+lk4*8
#pragma unroll
      for (int j = 0; j < 8; ++j) vtw[(lk4 * 8 + j) * 40 + lr] = (u16)v[j];
      // zero pad m in [16,32)
      *(short8*)&vtw[(l >> 1) * 40 + 16 + (l & 1) * 8] = z8;
    }
    // S (1 MFMA), C rows n = lk4*4+r, cols m = lr
    f32x4 s = mfma16(aq, bk, z);
#pragma unroll
    for (int r = 0; r < 4; ++r) {
      int n = lk4 * 4 + r;
      s[r] = s[r] * scale + bias4[(g * 16 + n) * 16 + lr];
    }
    float invden[4];
#pragma unroll
    for (int r = 0; r < 4; ++r) {
      float mx = s[r];
#pragma unroll
      for (int d = 1; d < 16; d <<= 1) mx = fmaxf(mx, __shfl_xor(mx, d));
      float p = __expf(s[r] - mx);
      s[r] = p;
      float sum = p;
#pragma unroll
      for (int d = 1; d < 16; d <<= 1) sum += __shfl_xor(sum, d);
      invden[r] = 1.f / sum;
    }
    // P -> LDS + zero pad
#pragma unroll
    for (int r = 0; r < 4; ++r) plw[(lk4 * 4 + r) * 40 + lr] = f2bf(s[r]);
    *(u16x4*)&plw[lr * 40 + 16 + lk4 * 4] = (u16x4){0, 0, 0, 0};
    wave_lds_fence();
    // O = P V : 2 MFMAs (te halves), K zero-padded to 32
    f32x4 o[2];
#pragma unroll
    for (int te = 0; te < 2; ++te) {
      short8 pa = *(const short8*)&plw[lr * 40 + lk4 * 8];
      short8 vb = *(const short8*)&vtw[(te * 16 + lr) * 40 + lk4 * 8];
      o[te] = mfma16(pa, vb, z);
    }
#pragma unroll
    for (int te = 0; te < 2; ++te)
#pragma unroll
      for (int r = 0; r < 4; ++r) {
        int n = lk4 * 4 + r;
        olw[n * 33 + te * 16 + lr] = o[te][r] * invden[r];
      }
    wave_lds_fence();
    // store: lane = (token lr) x (e-chunk lk4)
    {
      int h = h0 + (lr >> 2), w = w0 + (lr & 3);
      size_t base = ((size_t)(Bg >> 2)) * 4194304 +
                    (size_t)(((Bg & 3) * 2 + (h >> 5))) * 131072 +
                    (size_t)(((h >> 2) & 7)) * 16384 + (size_t)((h & 3) * 64 + w);
#pragma unroll
      for (int ee = 0; ee < 8; ++ee) {
        int e = lk4 * 8 + ee;
        int c = g * 32 + e;
        size_t idx = base + (size_t)(c >> 6) * 1048576 + (size_t)((c >> 3) & 7) * 2048 +
                     (size_t)(c & 7) * 256;
        out[idx] = olw[lr * 33 + e];
      }
    }
    wave_lds_fence();  // protect per-wave buffer reuse across g iterations
  }
}

extern "C" void kernel_launch(void* const* d_in, const int* in_sizes, int n_in,
                              void* d_out, int out_size, void* d_ws, size_t ws_size,
                              hipStream_t stream) {
  const float* x = (const float*)d_in[0];
  const float* qkv_w = (const float*)d_in[1];
  const float* qkv_b = (const float*)d_in[2];
  const float* t0 = (const float*)d_in[3];
  const float* t1 = (const float*)d_in[4];
  float* out = (float*)d_out;
  char* ws = (char*)d_ws;

  u16* qkvB = (u16*)ws;                         // 192*65536*4 u16  = 100663296 B
  u16* wb = (u16*)(ws + 100663296);             // 768*256*2        = 393216 B
  float* bias8 = (float*)(ws + 101056512);      // 4*64*64*4        = 65536 B
  float* bias4 = (float*)(ws + 101122048);      // 4*16*16*4        = 4096 B

  k_prep<<<256, 256, 0, stream>>>(qkv_w, t0, t1, wb, bias4, bias8);
  k_gemm<<<1024, 512, 0, stream>>>(x, wb, qkv_b, qkvB);
  k_attn8<<<1024, 256, 0, stream>>>(qkvB, bias8, out);
  k_attn4<<<1024, 256, 0, stream>>>(qkvB, bias4, out);
}